// Round 7
// baseline (849.001 us; speedup 1.0000x reference)
//
#include <hip/hip_runtime.h>

// ---------------------------------------------------------------------------
// Elastic 2D velocity-stress staggered FD + C-PML, 2 shots, 128 steps.
// Round 16: R15 base (proven 776us/dispatch, passed) + REGISTER-CACHED
// thread-private state. At 1024 threads every phase is single-pass, so the
// thread<->cell binding is fixed 1:1. The C-PML memory fields (mv*/ms*) are
// cell-private (no other thread ever reads them) and self fields / decay /
// buoyancy / Lame params are per-cell constants: all moved to registers.
// LDS keeps only the neighbor-visible tiles (vy,vx,syy,sxx,sxy). Cuts ~35%
// of LDS pipe traffic (the largest compute term: ~2.4us of the 6.06us step),
// removes 9 LDS arrays (81KB -> 29KB). Arithmetic order identical -> bit-
// identical output. Protocol/geometry/barriers untouched.
//  - R12 (lgkmcnt barriers, odd strides): regressed, reverted.
//  - R13 (TH=10 co-residency): failed correctness, reverted.
//  - R14/R15 (512/1024 thr): occupancy x4, dur -1% -> TLP exhausted; this
//    round attacks the LDS-pipe floor instead.
// ---------------------------------------------------------------------------

typedef unsigned long long ull;

#define NYI   300
#define NXI   300
#define PML   20
#define NYP   340
#define NXP   340
#define NT    128
#define DXC   5.0f
#define DTC   0.001f
#define NSHOT 2
#define NREC  32
#define C1C   (9.0f / 8.0f)
#define C2C   (-1.0f / 24.0f)
#define RDX   (1.0f / 5.0f)

#define PITCH   344
#define FSTRIDE (NYP * PITCH)

// tile grid per shot: 8 x 16 tiles
#define TX 8
#define TY 16
#define TW 43
#define TH 22
#define MH 30
#define MW 52
#define VH 26
#define VW 48

#define NTHR 1024

__device__ __forceinline__ ull aload(const ull* p) {
    return __hip_atomic_load(p, __ATOMIC_RELAXED, __HIP_MEMORY_SCOPE_AGENT);
}
__device__ __forceinline__ void pushv(ull* p, float v, unsigned tag) {
    ull u = ((ull)tag << 32) | (ull)__float_as_uint(v);
    __hip_atomic_store(p, u, __ATOMIC_RELAXED, __HIP_MEMORY_SCOPE_AGENT);
}
__device__ __forceinline__ float decay_at(int idx) {
    float fx = (float)idx;
    float lo = fminf(fmaxf(((float)PML - fx) / (float)PML, 0.0f), 1.0f);
    float hi = fminf(fmaxf((fx - (float)(NYP - 1 - PML)) / (float)PML, 0.0f), 1.0f);
    float mx = fmaxf(lo, hi);
    float d0 = 3.0f * 2000.0f / (2.0f * (float)PML * DXC) * logf(1.0f / 1e-6f);
    return expf(-d0 * mx * mx * DTC);
}
__device__ __forceinline__ int clampi(int v, int hi) {
    return v < 0 ? 0 : (v > hi ? hi : v);
}

__global__ void init_params_kernel(const float* __restrict__ lamb,
                                   const float* __restrict__ mu,
                                   const float* __restrict__ buo,
                                   float* __restrict__ params) {
    int x = blockIdx.x * blockDim.x + threadIdx.x;
    int y = blockIdx.y;
    if (x >= NXP || y >= NYP) return;
    int cy = y - PML; cy = cy < 0 ? 0 : (cy > NYI - 1 ? NYI - 1 : cy);
    int cx = x - PML; cx = cx < 0 ? 0 : (cx > NXI - 1 ? NXI - 1 : cx);
    float l = lamb[cy * NXI + cx];
    float m = mu[cy * NXI + cx];
    float b = buo[cy * NXI + cx];
    int idx = y * PITCH + x;
    params[0 * FSTRIDE + idx] = l;
    params[1 * FSTRIDE + idx] = l + 2.0f * m;
    params[2 * FSTRIDE + idx] = m;
    params[3 * FSTRIDE + idx] = b;
}

__global__ void init_decay_kernel(float* __restrict__ bdec) {
    int i = blockIdx.x * blockDim.x + threadIdx.x;
    if (i >= NYP + NXP) return;
    int idx = (i < NYP) ? i : i - NYP;
    bdec[i] = decay_at(idx);
}

__global__ __launch_bounds__(NTHR)
void persist6_kernel(ull* __restrict__ strips, const float* __restrict__ lamb,
                     const float* __restrict__ mu, const float* __restrict__ buo,
                     const float* __restrict__ amps,
                     const int* __restrict__ sloc, const int* __restrict__ rloc,
                     float* __restrict__ out) {
    __shared__ float syyR[MH][MW], sxxR[MH][MW], sxyR[MH][MW];
    __shared__ float vyR[VH][VW], vxR[VH][VW];

    const int tid = threadIdx.x;
    const int s = blockIdx.x >> 7, tile = blockIdx.x & 127;
    const int txi = tile & 7, tyi = tile >> 3;
    const int x0 = txi * TW, x1 = min(x0 + TW, NXP);
    const int y0 = tyi * TH, y1 = min(y0 + TH, NYP);
    const int w = x1 - x0, h = y1 - y0;

    // ---- zero the neighbor-visible LDS tiles ----
    for (int i = tid; i < MH * MW; i += NTHR) {
        int r = i / MW, c = i - r * MW;
        syyR[r][c] = 0.0f; sxxR[r][c] = 0.0f; sxyR[r][c] = 0.0f;
    }
    for (int i = tid; i < VH * VW; i += NTHR) {
        int r = i / VW, c = i - r * VW;
        vyR[r][c] = 0.0f; vxR[r][c] = 0.0f;
    }

    const int sy = sloc[s * 2 + 0] + PML;
    const int sx = sloc[s * 2 + 1] + PML;

    bool hasRec = false; int recOff = 0, rvi = 0, rvj = 0;
    if (tid < NSHOT * NREC) {
        int rs = tid >> 5, rr = tid & 31;
        if (rs == s) {
            int ry = rloc[(rs * NREC + rr) * 2 + 0] + PML;
            int rx = rloc[(rs * NREC + rr) * 2 + 1] + PML;
            if (ry >= y0 && ry < y1 && rx >= x0 && rx < x1) {
                hasRec = true; recOff = (rs * NREC + rr) * NT;
                rvi = ry - y0 + 2; rvj = rx - x0 + 2;
            }
        }
    }

    // region geometry (identical to R6/R7, validated)
    const int vy0 = max(y0 - 2, 0), vy1 = min(y1 + 2, NYP);
    const int vx0 = max(x0 - 2, 0), vx1 = min(x1 + 2, NXP);
    const int cy0 = y0 + 2, cy1 = y1 - 2, cx0 = x0 + 2, cx1 = x1 - 2;
    const int cw = cx1 - cx0, ch = cy1 - cy0, nCore = cw * ch;
    const int W2 = vx1 - vx0;
    const int topH = cy0 - vy0, botH = vy1 - cy1;
    const int leftW = cx0 - vx0, rightW = vx1 - cx1;
    const int nTop = topH * W2, nBot = botH * W2;
    const int nLeft = ch * leftW, nRight = ch * rightW;
    const int nRing = nTop + nBot + nLeft + nRight;
    const int py0 = max(y0 - 4, 0), py1 = min(y1 + 4, NYP);
    const int px0 = max(x0 - 4, 0), px1 = min(x1 + 4, NXP);
    const int W4 = px1 - px0;
    const int ptH = y0 - py0, pbH = py1 - y1;
    const int plW = x0 - px0, prW = px1 - x1;
    const int nPT = ptH * W4, nPB = pbH * W4, nPL = h * plW, nPR = h * prW;
    const int nPull = nPT + nPB + nPL + nPR;
    const int midH = h - 8, w8 = w - 8;
    const int nT4 = 4 * w, nB4 = 4 * w, nL4 = midH * 4;
    const int nD1 = nT4 + nB4 + 2 * nL4;
    const int nD2 = midH * w8;

    // ---- hoisted pull-cell decode (nPull <= 584 < 1024: one cell/thread) ----
    const bool hq0 = tid < nPull;
    int qg0 = 0, qo0 = 0;
    if (hq0) {
        int j = tid, y, x;
        if (j < nPT)            { y = py0 + j / W4;  x = px0 + j % W4; }
        else { j -= nPT;
        if (j < nPB)            { y = y1 + j / W4;   x = px0 + j % W4; }
        else { j -= nPB;
        if (j < nPL)            { y = y0 + j / plW;  x = px0 + j % plW; }
        else { j -= nPL;          y = y0 + j / prW;  x = x1 + j % prW; } } }
        qg0 = y * PITCH + x;
        qo0 = (y - y0 + 4) * MW + (x - x0 + 4);
    }
    float* const syyF = &syyR[0][0];
    float* const sxxF = &sxxR[0][0];
    float* const sxyF = &sxyR[0][0];

    // ---- per-thread persistent cell state (fixed 1:1 binding, all phases
    //      single-pass at 1024 threads). m-fields/self-fields/constants in
    //      registers; LDS only holds neighbor-visible v and stress tiles. ----
    // core velocity cell
    const bool hasC = tid < nCore;
    int chy = 0, chx = 0; bool srcC = false;
    float cby = 1.0f, cbx = 1.0f, cbuo = 0.0f;
    float c_vy = 0.0f, c_vx = 0.0f, c_m0 = 0.0f, c_m1 = 0.0f, c_m2 = 0.0f, c_m3 = 0.0f;
    if (hasC) {
        int r = tid / cw, c = tid - r * cw;
        int y = cy0 + r, x = cx0 + c;
        chy = y - y0 + 4; chx = x - x0 + 4;
        srcC = (y == sy && x == sx);
        cby = decay_at(y); cbx = decay_at(x);
        cbuo = buo[clampi(y - PML, NYI - 1) * NXI + clampi(x - PML, NXI - 1)];
    }
    // ring velocity cell
    const bool hasRg = tid < nRing;
    int rhy = 0, rhx = 0; bool srcR = false;
    float rby = 1.0f, rbx = 1.0f, rbuo = 0.0f;
    float r_vy = 0.0f, r_vx = 0.0f, r_m0 = 0.0f, r_m1 = 0.0f, r_m2 = 0.0f, r_m3 = 0.0f;
    if (hasRg) {
        int j = tid, y, x;
        if (j < nTop)           { y = vy0 + j / W2;     x = vx0 + j % W2; }
        else { j -= nTop;
        if (j < nBot)           { y = cy1 + j / W2;     x = vx0 + j % W2; }
        else { j -= nBot;
        if (j < nLeft)          { y = cy0 + j / leftW;  x = vx0 + j % leftW; }
        else { j -= nLeft;        y = cy0 + j / rightW; x = cx1 + j % rightW; } } }
        rhy = y - y0 + 4; rhx = x - x0 + 4;
        srcR = (y == sy && x == sx);
        rby = decay_at(y); rbx = decay_at(x);
        rbuo = buo[clampi(y - PML, NYI - 1) * NXI + clampi(x - PML, NXI - 1)];
    }
    // D1 stress cell (boundary, published)
    const bool hasS1 = tid < nD1;
    int e1hy = 0, e1hx = 0, e1gi = 0;
    float e1by = 1.0f, e1bx = 1.0f, e1lam = 0.0f, e1lp2m = 0.0f, e1mu = 0.0f;
    float e1_syy = 0.0f, e1_sxx = 0.0f, e1_sxy = 0.0f;
    float e1_s0 = 0.0f, e1_s1 = 0.0f, e1_s2 = 0.0f, e1_s3 = 0.0f;
    if (hasS1) {
        int j = tid, ly, lx;
        if (j < nT4)      { ly = j / w;           lx = j - (j / w) * w; }
        else { j -= nT4;
        if (j < nB4)      { ly = h - 4 + j / w;   lx = j - (j / w) * w; }
        else { j -= nB4;
        if (j < nL4)      { ly = 4 + (j >> 2);    lx = j & 3; }
        else { j -= nL4;    ly = 4 + (j >> 2);    lx = w - 4 + (j & 3); } } }
        int y = y0 + ly, x = x0 + lx;
        e1hy = ly + 4; e1hx = lx + 4;
        e1gi = y * PITCH + x;
        e1by = decay_at(y); e1bx = decay_at(x);
        int yy = clampi(y - PML, NYI - 1), xx = clampi(x - PML, NXI - 1);
        float l = lamb[yy * NXI + xx], m = mu[yy * NXI + xx];
        e1lam = l; e1lp2m = l + 2.0f * m; e1mu = m;
    }
    // D2 stress cell (interior, not published)
    const bool hasS2 = tid < nD2;
    int f2hy = 0, f2hx = 0;
    float f2by = 1.0f, f2bx = 1.0f, f2lam = 0.0f, f2lp2m = 0.0f, f2mu = 0.0f;
    float f2_syy = 0.0f, f2_sxx = 0.0f, f2_sxy = 0.0f;
    float f2_s0 = 0.0f, f2_s1 = 0.0f, f2_s2 = 0.0f, f2_s3 = 0.0f;
    if (hasS2) {
        int r = tid / w8, c = tid - r * w8;
        int ly = 4 + r, lx = 4 + c;
        int y = y0 + ly, x = x0 + lx;
        f2hy = ly + 4; f2hx = lx + 4;
        f2by = decay_at(y); f2bx = decay_at(x);
        int yy = clampi(y - PML, NYI - 1), xx = clampi(x - PML, NXI - 1);
        float l = lamb[yy * NXI + xx], m = mu[yy * NXI + xx];
        f2lam = l; f2lp2m = l + 2.0f * m; f2mu = m;
    }
    __syncthreads();

    // velocity update: stress stencil from LDS; m/b/buo/self-v in registers.
    auto doVreg = [&](int hy, int hx, bool isSrc, float amp,
                      float by, float bx, float buov,
                      float& vyp, float& vxp,
                      float& m0, float& m1, float& m2, float& m3) {
        int vi = hy - 2, vj = hx - 2;
        float d1 = (C1C * (syyR[hy + 1][hx] - syyR[hy][hx]) +
                    C2C * (syyR[hy + 2][hx] - syyR[hy - 1][hx])) * RDX;   // dpy(syy)
        m0 = by * m0 + (by - 1.0f) * d1;
        float d2 = (C1C * (sxyR[hy][hx] - sxyR[hy][hx - 1]) +
                    C2C * (sxyR[hy][hx + 1] - sxyR[hy][hx - 2])) * RDX;   // dmx(sxy)
        m1 = bx * m1 + (bx - 1.0f) * d2;
        float nvy = vyp + DTC * buov * (d1 + m0 + d2 + m1);
        float d3 = (C1C * (sxyR[hy][hx] - sxyR[hy - 1][hx]) +
                    C2C * (sxyR[hy + 1][hx] - sxyR[hy - 2][hx])) * RDX;   // dmy(sxy)
        m2 = by * m2 + (by - 1.0f) * d3;
        float d4 = (C1C * (sxxR[hy][hx + 1] - sxxR[hy][hx]) +
                    C2C * (sxxR[hy][hx + 2] - sxxR[hy][hx - 1])) * RDX;   // dpx(sxx)
        m3 = bx * m3 + (bx - 1.0f) * d4;
        float nvx = vxp + DTC * buov * (d3 + m2 + d4 + m3);
        if (isSrc) nvy += amp;
        vyp = nvy; vxp = nvx;
        vyR[vi][vj] = nvy; vxR[vi][vj] = nvx;
    };

    // stress update: v stencil from LDS; m/b/params/self-stress in registers.
    auto doSreg = [&](int hy, int hx, float by, float bx,
                      float lam, float lp2m, float muv,
                      float& syyp, float& sxxp, float& sxyp,
                      float& s0, float& s1, float& s2, float& s3,
                      bool pub, ull* cellp, unsigned tag) {
        int vi = hy - 2, vj = hx - 2;
        float d;
        d = (C1C * (vyR[vi][vj] - vyR[vi - 1][vj]) +
             C2C * (vyR[vi + 1][vj] - vyR[vi - 2][vj])) * RDX;            // dmy(vy)
        s0 = by * s0 + (by - 1.0f) * d;
        float dvy_dy = d + s0;
        d = (C1C * (vxR[vi][vj] - vxR[vi][vj - 1]) +
             C2C * (vxR[vi][vj + 1] - vxR[vi][vj - 2])) * RDX;            // dmx(vx)
        s1 = bx * s1 + (bx - 1.0f) * d;
        float dvx_dx = d + s1;
        float nsyy = syyp + DTC * (lp2m * dvy_dy + lam * dvx_dx);
        float nsxx = sxxp + DTC * (lp2m * dvx_dx + lam * dvy_dy);
        d = (C1C * (vyR[vi][vj + 1] - vyR[vi][vj]) +
             C2C * (vyR[vi][vj + 2] - vyR[vi][vj - 1])) * RDX;            // dpx(vy)
        s2 = bx * s2 + (bx - 1.0f) * d;
        float dvy_dx = d + s2;
        d = (C1C * (vxR[vi + 1][vj] - vxR[vi][vj]) +
             C2C * (vxR[vi + 2][vj] - vxR[vi - 1][vj])) * RDX;            // dpy(vx)
        s3 = by * s3 + (by - 1.0f) * d;
        float dvx_dy = d + s3;
        float nsxy = sxyp + DTC * muv * (dvy_dx + dvx_dy);
        syyp = nsyy; sxxp = nsxx; sxyp = nsxy;
        syyR[hy][hx] = nsyy;
        sxxR[hy][hx] = nsxx;
        sxyR[hy][hx] = nsxy;
        if (pub) {
            pushv(cellp, nsyy, tag);
            pushv(cellp + 1, nsxx, tag);
            pushv(cellp + 2, nsxy, tag);
        }
    };

    for (int t = 0; t < NT; ++t) {
        const float amp_t = amps[s * NT + t];

        // ---- B-issue: fire the halo pull loads up front (latency hides
        //      under the A-phase compute) ----
        const ull* bb = strips + (size_t)(((t ^ 1) & 1) * NSHOT + s) * 4 * FSTRIDE;
        const unsigned want = (unsigned)t;
        const ull* qp0 = bb + (size_t)qg0 * 4;
        ull ua0 = 0, ub0 = 0, uc0 = 0;
        if (hq0) { ua0 = aload(qp0); ub0 = aload(qp0 + 1); uc0 = aload(qp0 + 2); }

        // ---- A: velocity core (block-local; overlaps in-flight pulls) ----
        if (hasC) doVreg(chy, chx, srcC, amp_t, cby, cbx, cbuo,
                         c_vy, c_vx, c_m0, c_m1, c_m2, c_m3);

        // ---- B-resolve: tag-check (spin only if neighbor is late) ----
        if (hq0) {
            while ((unsigned)(ua0 >> 32) != want) {
                __builtin_amdgcn_s_sleep(1); ua0 = aload(qp0);
            }
            syyF[qo0] = __uint_as_float((unsigned)ua0);
            while ((unsigned)(ub0 >> 32) != want) {
                __builtin_amdgcn_s_sleep(1); ub0 = aload(qp0 + 1);
            }
            sxxF[qo0] = __uint_as_float((unsigned)ub0);
            while ((unsigned)(uc0 >> 32) != want) {
                __builtin_amdgcn_s_sleep(1); uc0 = aload(qp0 + 2);
            }
            sxyF[qo0] = __uint_as_float((unsigned)uc0);
        }
        __syncthreads();

        // ---- C: velocity ring (+2 redundant, needs the pulled halo) ----
        if (hasRg) doVreg(rhy, rhx, srcR, amp_t, rby, rbx, rbuo,
                          r_vy, r_vx, r_m0, r_m1, r_m2, r_m3);
        __syncthreads();

        if (hasRec) out[recOff + t] = vyR[rvi][rvj];

        // ---- D1: boundary stress (depth<4), publish immediately (tag t+1);
        //      D2: interior stress (off the inter-block critical path) ----
        {
            ull* pb = strips + (size_t)((t & 1) * NSHOT + s) * 4 * FSTRIDE;
            const unsigned tag = (unsigned)(t + 1);
            if (hasS1) doSreg(e1hy, e1hx, e1by, e1bx, e1lam, e1lp2m, e1mu,
                              e1_syy, e1_sxx, e1_sxy, e1_s0, e1_s1, e1_s2, e1_s3,
                              true, pb + (size_t)e1gi * 4, tag);
            if (hasS2) doSreg(f2hy, f2hx, f2by, f2bx, f2lam, f2lp2m, f2mu,
                              f2_syy, f2_sxx, f2_sxy, f2_s0, f2_s1, f2_s2, f2_s3,
                              false, (ull*)0, 0u);
        }
        __syncthreads();
    }
}

// ------------------------------ fallback path (R1, proven) ------------------

__global__ __launch_bounds__(256)
void vel_kernel(float* __restrict__ ws, const float* __restrict__ params,
                const float* __restrict__ bdec, const float* __restrict__ amps,
                const int* __restrict__ sloc, int t) {
    int x = blockIdx.x * 64 + threadIdx.x;
    int y = blockIdx.y * 4 + threadIdx.y;
    int s = blockIdx.z;
    if (x >= NXP) return;
    float* F = ws + (size_t)s * 13 * FSTRIDE;
    float* vy = F; float* vx = F + FSTRIDE;
    const float* syy = F + 2 * FSTRIDE;
    const float* sxx = F + 3 * FSTRIDE;
    const float* sxy = F + 4 * FSTRIDE;
    float* msyy_y = F + 9 * FSTRIDE;  float* msxy_x = F + 10 * FSTRIDE;
    float* msxy_y = F + 11 * FSTRIDE; float* msxx_x = F + 12 * FSTRIDE;
    float by = bdec[y], bx = bdec[NYP + x];
    int idx = y * PITCH + x;
    auto ldf2 = [&](const float* f, int yy, int xx) {
        return (yy >= 0 && yy < NYP && xx >= 0 && xx < NXP) ? f[yy * PITCH + xx] : 0.0f;
    };
    float buoy = params[3 * FSTRIDE + idx];
    float d, m;
    d = (C1C * (ldf2(syy,y+1,x) - ldf2(syy,y,x)) + C2C * (ldf2(syy,y+2,x) - ldf2(syy,y-1,x))) * RDX;
    m = by * msyy_y[idx] + (by - 1.0f) * d; msyy_y[idx] = m;
    float a1 = d + m;
    d = (C1C * (ldf2(sxy,y,x) - ldf2(sxy,y,x-1)) + C2C * (ldf2(sxy,y,x+1) - ldf2(sxy,y,x-2))) * RDX;
    m = bx * msxy_x[idx] + (bx - 1.0f) * d; msxy_x[idx] = m;
    float nvy = vy[idx] + DTC * buoy * (a1 + d + m);
    d = (C1C * (ldf2(sxy,y,x) - ldf2(sxy,y-1,x)) + C2C * (ldf2(sxy,y+1,x) - ldf2(sxy,y-2,x))) * RDX;
    m = by * msxy_y[idx] + (by - 1.0f) * d; msxy_y[idx] = m;
    float a2 = d + m;
    d = (C1C * (ldf2(sxx,y,x+1) - ldf2(sxx,y,x)) + C2C * (ldf2(sxx,y,x+2) - ldf2(sxx,y,x-1))) * RDX;
    m = bx * msxx_x[idx] + (bx - 1.0f) * d; msxx_x[idx] = m;
    float nvx = vx[idx] + DTC * buoy * (a2 + d + m);
    int sy = sloc[s * 2 + 0] + PML, sx = sloc[s * 2 + 1] + PML;
    if (y == sy && x == sx) nvy += amps[s * NT + t];
    vy[idx] = nvy; vx[idx] = nvx;
}

__global__ __launch_bounds__(256)
void str_kernel(float* __restrict__ ws, const float* __restrict__ params,
                const float* __restrict__ bdec, const int* __restrict__ rloc,
                float* __restrict__ out, int t) {
    int x = blockIdx.x * 64 + threadIdx.x;
    int y = blockIdx.y * 4 + threadIdx.y;
    int s = blockIdx.z;
    float* F = ws + (size_t)s * 13 * FSTRIDE;
    const float* vy = F; const float* vx = F + FSTRIDE;
    float* syy = F + 2 * FSTRIDE; float* sxx = F + 3 * FSTRIDE; float* sxy = F + 4 * FSTRIDE;
    float* mvyy = F + 5 * FSTRIDE; float* mvyx = F + 6 * FSTRIDE;
    float* mvxy = F + 7 * FSTRIDE; float* mvxx = F + 8 * FSTRIDE;
    if (blockIdx.x == 0 && blockIdx.y == 0) {
        int tid = threadIdx.y * 64 + threadIdx.x;
        if (tid < NREC) {
            int ry = rloc[(s * NREC + tid) * 2 + 0] + PML;
            int rx = rloc[(s * NREC + tid) * 2 + 1] + PML;
            out[(s * NREC + tid) * NT + t] = vy[ry * PITCH + rx];
        }
    }
    if (x >= NXP) return;
    auto ldf2 = [&](const float* f, int yy, int xx) {
        return (yy >= 0 && yy < NYP && xx >= 0 && xx < NXP) ? f[yy * PITCH + xx] : 0.0f;
    };
    float by = bdec[y], bx = bdec[NYP + x];
    int idx = y * PITCH + x;
    float lam = params[idx], lp2m = params[FSTRIDE + idx], muv = params[2 * FSTRIDE + idx];
    float d, m;
    d = (C1C * (ldf2(vy,y,x) - ldf2(vy,y-1,x)) + C2C * (ldf2(vy,y+1,x) - ldf2(vy,y-2,x))) * RDX;
    m = by * mvyy[idx] + (by - 1.0f) * d; mvyy[idx] = m;
    float dvy_dy = d + m;
    d = (C1C * (ldf2(vx,y,x) - ldf2(vx,y,x-1)) + C2C * (ldf2(vx,y,x+1) - ldf2(vx,y,x-2))) * RDX;
    m = bx * mvxx[idx] + (bx - 1.0f) * d; mvxx[idx] = m;
    float dvx_dx = d + m;
    syy[idx] += DTC * (lp2m * dvy_dy + lam * dvx_dx);
    sxx[idx] += DTC * (lp2m * dvx_dx + lam * dvy_dy);
    d = (C1C * (ldf2(vy,y,x+1) - ldf2(vy,y,x)) + C2C * (ldf2(vy,y,x+2) - ldf2(vy,y,x-1))) * RDX;
    m = bx * mvyx[idx] + (bx - 1.0f) * d; mvyx[idx] = m;
    float dvy_dx = d + m;
    d = (C1C * (ldf2(vx,y+1,x) - ldf2(vx,y,x)) + C2C * (ldf2(vx,y+2,x) - ldf2(vx,y-1,x))) * RDX;
    m = by * mvxy[idx] + (by - 1.0f) * d; mvxy[idx] = m;
    float dvx_dy = d + m;
    sxy[idx] += DTC * muv * (dvy_dx + dvx_dy);
}

// ----------------------------------------------------------------------------

extern "C" void kernel_launch(void* const* d_in, const int* in_sizes, int n_in,
                              void* d_out, int out_size, void* d_ws, size_t ws_size,
                              hipStream_t stream) {
    const float* lamb = (const float*)d_in[0];
    const float* mu   = (const float*)d_in[1];
    const float* buo  = (const float*)d_in[2];
    const float* amps = (const float*)d_in[3];
    const int*   sloc = (const int*)d_in[4];
    const int*   rloc = (const int*)d_in[5];
    float* out = (float*)d_out;

    float* wsf = (float*)d_ws;
    // layout: [strips: 16*FSTRIDE ull (2 parities x 2 shots x 4-ull cell records)]
    //         (persist path computes params/decay inline; region after strips
    //          unused there but kept in the `needed` check for layout parity)
    ull*   strips = (ull*)wsf;
    size_t needed = ((size_t)36 * FSTRIDE + NYP + NXP) * sizeof(float);

    if (ws_size >= needed) {
        (void)hipMemsetAsync(strips, 0, (size_t)16 * FSTRIDE * sizeof(ull), stream);
        void* args[] = {&strips, &lamb, &mu, &buo, &amps, &sloc, &rloc, &out};
        (void)hipLaunchCooperativeKernel((void*)persist6_kernel, dim3(NSHOT * TX * TY),
                                         dim3(NTHR), args, 0, stream);
    } else {
        dim3 pib(256, 1, 1), pig((NXP + 255) / 256, NYP, 1);
        float* statef = wsf + 64;
        float* paramf = wsf + 64 + (size_t)26 * FSTRIDE;
        float* bdecf  = wsf + 64 + (size_t)30 * FSTRIDE;
        (void)hipMemsetAsync(statef, 0, (size_t)26 * FSTRIDE * sizeof(float), stream);
        init_params_kernel<<<pig, pib, 0, stream>>>(lamb, mu, buo, paramf);
        init_decay_kernel<<<(NYP + NXP + 255) / 256, 256, 0, stream>>>(bdecf);
        dim3 blk(64, 4, 1), grd((NXP + 63) / 64, NYP / 4, NSHOT);
        for (int t = 0; t < NT; ++t) {
            vel_kernel<<<grd, blk, 0, stream>>>(statef, paramf, bdecf, amps, sloc, t);
            str_kernel<<<grd, blk, 0, stream>>>(statef, paramf, bdecf, rloc, out, t);
        }
    }
}

// Round 8
// 816.057 us; speedup vs baseline: 1.0404x; 1.0404x over previous
//
#include <hip/hip_runtime.h>

// ---------------------------------------------------------------------------
// Elastic 2D velocity-stress staggered FD + C-PML, 2 shots, 128 steps.
// Round 17: R15 structure VERBATIM (proven 776us, passed; tile-size-generic
// strided loops) with BIGGER TILES: 43x44 (TH 22->44, TY 16->8), 128 blocks.
// Theory: every round's dur == hbm_bytes / ~2.1 TB/s, and WRITE_SIZE is
// constant == #publish-stores x 32B (8B agent atomics bypass L2 -> one ~32B
// LLC transaction each). The kernel is ATOMIC-TRANSACTION-bound. Fewer,
// squarer tiles cut boundary transactions: stores/step -31%, loads -35%.
//  - R16 (register-cached state): cut LDS ops 45%, dur REGRESSED 7% ->
//    LDS pipe was never binding; reverted.
//  - R14/R15 (512/1024 thr): occupancy x4, dur -1% -> TLP exhausted.
// LDS 148KB static (>64KB proven OK on gfx950: 81KB ran R10-R15; limit 160K).
// ---------------------------------------------------------------------------

typedef unsigned long long ull;

#define NYI   300
#define NXI   300
#define PML   20
#define NYP   340
#define NXP   340
#define NT    128
#define DXC   5.0f
#define DTC   0.001f
#define NSHOT 2
#define NREC  32
#define C1C   (9.0f / 8.0f)
#define C2C   (-1.0f / 24.0f)
#define RDX   (1.0f / 5.0f)

#define PITCH   344
#define FSTRIDE (NYP * PITCH)

// tile grid per shot: 8 x 8 tiles of 43 x 44
#define TX 8
#define TY 8
#define TPS (TX * TY)      /* 64 tiles per shot */
#define TW 43
#define TH 44
#define MH (TH + 8)        /* 52 */
#define MW 52
#define VH (TH + 4)        /* 48 */
#define VW 48
#define IH TH              /* 44 */
#define IW 44

#define NTHR 1024

__device__ __forceinline__ ull aload(const ull* p) {
    return __hip_atomic_load(p, __ATOMIC_RELAXED, __HIP_MEMORY_SCOPE_AGENT);
}
__device__ __forceinline__ void pushv(ull* p, float v, unsigned tag) {
    ull u = ((ull)tag << 32) | (ull)__float_as_uint(v);
    __hip_atomic_store(p, u, __ATOMIC_RELAXED, __HIP_MEMORY_SCOPE_AGENT);
}
__device__ __forceinline__ float decay_at(int idx) {
    float fx = (float)idx;
    float lo = fminf(fmaxf(((float)PML - fx) / (float)PML, 0.0f), 1.0f);
    float hi = fminf(fmaxf((fx - (float)(NYP - 1 - PML)) / (float)PML, 0.0f), 1.0f);
    float mx = fmaxf(lo, hi);
    float d0 = 3.0f * 2000.0f / (2.0f * (float)PML * DXC) * logf(1.0f / 1e-6f);
    return expf(-d0 * mx * mx * DTC);
}
__device__ __forceinline__ int clampi(int v, int hi) {
    return v < 0 ? 0 : (v > hi ? hi : v);
}

__global__ void init_params_kernel(const float* __restrict__ lamb,
                                   const float* __restrict__ mu,
                                   const float* __restrict__ buo,
                                   float* __restrict__ params) {
    int x = blockIdx.x * blockDim.x + threadIdx.x;
    int y = blockIdx.y;
    if (x >= NXP || y >= NYP) return;
    int cy = y - PML; cy = cy < 0 ? 0 : (cy > NYI - 1 ? NYI - 1 : cy);
    int cx = x - PML; cx = cx < 0 ? 0 : (cx > NXI - 1 ? NXI - 1 : cx);
    float l = lamb[cy * NXI + cx];
    float m = mu[cy * NXI + cx];
    float b = buo[cy * NXI + cx];
    int idx = y * PITCH + x;
    params[0 * FSTRIDE + idx] = l;
    params[1 * FSTRIDE + idx] = l + 2.0f * m;
    params[2 * FSTRIDE + idx] = m;
    params[3 * FSTRIDE + idx] = b;
}

__global__ void init_decay_kernel(float* __restrict__ bdec) {
    int i = blockIdx.x * blockDim.x + threadIdx.x;
    if (i >= NYP + NXP) return;
    int idx = (i < NYP) ? i : i - NYP;
    bdec[i] = decay_at(idx);
}

__global__ __launch_bounds__(NTHR)
void persist6_kernel(ull* __restrict__ strips, const float* __restrict__ lamb,
                     const float* __restrict__ mu, const float* __restrict__ buo,
                     const float* __restrict__ amps,
                     const int* __restrict__ sloc, const int* __restrict__ rloc,
                     float* __restrict__ out) {
    __shared__ float syyR[MH][MW], sxxR[MH][MW], sxyR[MH][MW];
    __shared__ float vyR[VH][VW], vxR[VH][VW];
    __shared__ float mv0[VH][VW], mv1[VH][VW], mv2[VH][VW], mv3[VH][VW];
    __shared__ float ms0[IH][IW], ms1[IH][IW], ms2[IH][IW], ms3[IH][IW];
    __shared__ float buoL[VH][VW];
    __shared__ float lamL[IH][IW], lp2mL[IH][IW], muL[IH][IW];
    __shared__ float byL[VH], bxL[VW];

    const int tid = threadIdx.x;
    const int s = blockIdx.x >> 6, tile = blockIdx.x & 63;
    const int txi = tile & 7, tyi = tile >> 3;
    const int x0 = txi * TW, x1 = min(x0 + TW, NXP);
    const int y0 = tyi * TH, y1 = min(y0 + TH, NYP);
    const int w = x1 - x0, h = y1 - y0;

    // ---- zero LDS state; compute params/decay directly into LDS ----
    for (int i = tid; i < MH * MW; i += NTHR) {
        int r = i / MW, c = i - r * MW;
        syyR[r][c] = 0.0f; sxxR[r][c] = 0.0f; sxyR[r][c] = 0.0f;
    }
    for (int i = tid; i < VH * VW; i += NTHR) {
        int r = i / VW, c = i - r * VW;
        vyR[r][c] = 0.0f; vxR[r][c] = 0.0f;
        mv0[r][c] = 0.0f; mv1[r][c] = 0.0f; mv2[r][c] = 0.0f; mv3[r][c] = 0.0f;
        buoL[r][c] = 0.0f;
    }
    for (int i = tid; i < IH * IW; i += NTHR) {
        int r = i / IW, c = i - r * IW;
        ms0[r][c] = 0.0f; ms1[r][c] = 0.0f; ms2[r][c] = 0.0f; ms3[r][c] = 0.0f;
    }
    if (tid < VH) {
        int y = y0 - 2 + tid; y = min(max(y, 0), NYP - 1);
        byL[tid] = decay_at(y);
    } else if (tid >= 64 && tid < 64 + VW) {
        int i = tid - 64, x = x0 - 2 + i; x = min(max(x, 0), NXP - 1);
        bxL[i] = decay_at(x);
    }
    __syncthreads();
    {
        int ry0v = max(y0 - 2, 0), ry1v = min(y1 + 2, NYP);
        int rx0v = max(x0 - 2, 0), rx1v = min(x1 + 2, NXP);
        int rh = ry1v - ry0v, rw = rx1v - rx0v;
        for (int i = tid; i < rh * rw; i += NTHR) {
            int r = i / rw, c = i - r * rw;
            int y = ry0v + r, x = rx0v + c;
            int cy = clampi(y - PML, NYI - 1), cx = clampi(x - PML, NXI - 1);
            buoL[y - y0 + 2][x - x0 + 2] = buo[cy * NXI + cx];
        }
        for (int i = tid; i < h * w; i += NTHR) {
            int r = i / w, c = i - r * w;
            int cy = clampi(y0 + r - PML, NYI - 1), cx = clampi(x0 + c - PML, NXI - 1);
            float l = lamb[cy * NXI + cx];
            float m = mu[cy * NXI + cx];
            lamL[r][c] = l;
            lp2mL[r][c] = l + 2.0f * m;
            muL[r][c] = m;
        }
    }

    const int sy = sloc[s * 2 + 0] + PML;
    const int sx = sloc[s * 2 + 1] + PML;

    bool hasRec = false; int recOff = 0, rvi = 0, rvj = 0;
    if (tid < NSHOT * NREC) {
        int rs = tid >> 5, rr = tid & 31;
        if (rs == s) {
            int ry = rloc[(rs * NREC + rr) * 2 + 0] + PML;
            int rx = rloc[(rs * NREC + rr) * 2 + 1] + PML;
            if (ry >= y0 && ry < y1 && rx >= x0 && rx < x1) {
                hasRec = true; recOff = (rs * NREC + rr) * NT;
                rvi = ry - y0 + 2; rvj = rx - x0 + 2;
            }
        }
    }
    __syncthreads();

    // region geometry (identical scheme to R6/R7, tile-size-generic)
    const int vy0 = max(y0 - 2, 0), vy1 = min(y1 + 2, NYP);
    const int vx0 = max(x0 - 2, 0), vx1 = min(x1 + 2, NXP);
    const int cy0 = y0 + 2, cy1 = y1 - 2, cx0 = x0 + 2, cx1 = x1 - 2;
    const int cw = cx1 - cx0, ch = cy1 - cy0, nCore = cw * ch;
    const int W2 = vx1 - vx0;
    const int topH = cy0 - vy0, botH = vy1 - cy1;
    const int leftW = cx0 - vx0, rightW = vx1 - cx1;
    const int nTop = topH * W2, nBot = botH * W2;
    const int nLeft = ch * leftW, nRight = ch * rightW;
    const int nRing = nTop + nBot + nLeft + nRight;
    const int py0 = max(y0 - 4, 0), py1 = min(y1 + 4, NYP);
    const int px0 = max(x0 - 4, 0), px1 = min(x1 + 4, NXP);
    const int W4 = px1 - px0;
    const int ptH = y0 - py0, pbH = py1 - y1;
    const int plW = x0 - px0, prW = px1 - x1;
    const int nPT = ptH * W4, nPB = pbH * W4, nPL = h * plW, nPR = h * prW;
    const int nPull = nPT + nPB + nPL + nPR;

    // ---- hoisted pull-cell decode (time-invariant; nPull <= 760 < 1024) ----
    const bool hq0 = tid < nPull;
    const bool hq1 = tid + NTHR < nPull;   // always false at 1024, kept generic
    int qg0 = 0, qo0 = 0, qg1 = 0, qo1 = 0;
    {
        auto decode = [&](int j, int& g, int& o) {
            int y, x;
            if (j < nPT)            { y = py0 + j / W4;  x = px0 + j % W4; }
            else { j -= nPT;
            if (j < nPB)            { y = y1 + j / W4;   x = px0 + j % W4; }
            else { j -= nPB;
            if (j < nPL)            { y = y0 + j / plW;  x = px0 + j % plW; }
            else { j -= nPL;          y = y0 + j / prW;  x = x1 + j % prW; } } }
            g = y * PITCH + x;
            o = (y - y0 + 4) * MW + (x - x0 + 4);
        };
        if (hq0) decode(tid,        qg0, qo0);
        if (hq1) decode(tid + NTHR, qg1, qo1);
    }
    float* const syyF = &syyR[0][0];
    float* const sxxF = &sxxR[0][0];
    float* const sxyF = &sxyR[0][0];

    auto doV = [&](int y, int x, float amp) {
        int hy = y - y0 + 4, hx = x - x0 + 4;
        int vi = y - y0 + 2, vj = x - x0 + 2;
        float by = byL[vi], bx = bxL[vj];
        float d1 = (C1C * (syyR[hy + 1][hx] - syyR[hy][hx]) +
                    C2C * (syyR[hy + 2][hx] - syyR[hy - 1][hx])) * RDX;   // dpy(syy)
        float m1 = by * mv0[vi][vj] + (by - 1.0f) * d1; mv0[vi][vj] = m1;
        float d2 = (C1C * (sxyR[hy][hx] - sxyR[hy][hx - 1]) +
                    C2C * (sxyR[hy][hx + 1] - sxyR[hy][hx - 2])) * RDX;   // dmx(sxy)
        float m2 = bx * mv1[vi][vj] + (bx - 1.0f) * d2; mv1[vi][vj] = m2;
        float nvy = vyR[vi][vj] + DTC * buoL[vi][vj] * (d1 + m1 + d2 + m2);
        float d3 = (C1C * (sxyR[hy][hx] - sxyR[hy - 1][hx]) +
                    C2C * (sxyR[hy + 1][hx] - sxyR[hy - 2][hx])) * RDX;   // dmy(sxy)
        float m3 = by * mv2[vi][vj] + (by - 1.0f) * d3; mv2[vi][vj] = m3;
        float d4 = (C1C * (sxxR[hy][hx + 1] - sxxR[hy][hx]) +
                    C2C * (sxxR[hy][hx + 2] - sxxR[hy][hx - 1])) * RDX;   // dpx(sxx)
        float m4 = bx * mv3[vi][vj] + (bx - 1.0f) * d4; mv3[vi][vj] = m4;
        float nvx = vxR[vi][vj] + DTC * buoL[vi][vj] * (d3 + m3 + d4 + m4);
        if (y == sy && x == sx) nvy += amp;
        vyR[vi][vj] = nvy; vxR[vi][vj] = nvx;
    };

    auto doS = [&](int ly, int lx, ull* q, unsigned tag, bool pub) {
        int vi = ly + 2, vj = lx + 2;
        float by = byL[vi], bx = bxL[vj];
        float d, m;
        d = (C1C * (vyR[vi][vj] - vyR[vi - 1][vj]) +
             C2C * (vyR[vi + 1][vj] - vyR[vi - 2][vj])) * RDX;            // dmy(vy)
        m = by * ms0[ly][lx] + (by - 1.0f) * d; ms0[ly][lx] = m;
        float dvy_dy = d + m;
        d = (C1C * (vxR[vi][vj] - vxR[vi][vj - 1]) +
             C2C * (vxR[vi][vj + 1] - vxR[vi][vj - 2])) * RDX;            // dmx(vx)
        m = bx * ms1[ly][lx] + (bx - 1.0f) * d; ms1[ly][lx] = m;
        float dvx_dx = d + m;
        float nsyy = syyR[ly + 4][lx + 4] + DTC * (lp2mL[ly][lx] * dvy_dy + lamL[ly][lx] * dvx_dx);
        float nsxx = sxxR[ly + 4][lx + 4] + DTC * (lp2mL[ly][lx] * dvx_dx + lamL[ly][lx] * dvy_dy);
        d = (C1C * (vyR[vi][vj + 1] - vyR[vi][vj]) +
             C2C * (vyR[vi][vj + 2] - vyR[vi][vj - 1])) * RDX;            // dpx(vy)
        m = bx * ms2[ly][lx] + (bx - 1.0f) * d; ms2[ly][lx] = m;
        float dvy_dx = d + m;
        d = (C1C * (vxR[vi + 1][vj] - vxR[vi][vj]) +
             C2C * (vxR[vi + 2][vj] - vxR[vi - 1][vj])) * RDX;            // dpy(vx)
        m = by * ms3[ly][lx] + (by - 1.0f) * d; ms3[ly][lx] = m;
        float dvx_dy = d + m;
        float nsxy = sxyR[ly + 4][lx + 4] + DTC * muL[ly][lx] * (dvy_dx + dvx_dy);
        syyR[ly + 4][lx + 4] = nsyy;
        sxxR[ly + 4][lx + 4] = nsxx;
        sxyR[ly + 4][lx + 4] = nsxy;
        if (pub) {
            int gi = (y0 + ly) * PITCH + (x0 + lx);
            ull* c = q + (size_t)gi * 4;
            pushv(c, nsyy, tag);
            pushv(c + 1, nsxx, tag);
            pushv(c + 2, nsxy, tag);
        }
    };

    for (int t = 0; t < NT; ++t) {
        const float amp_t = amps[s * NT + t];

        // ---- B-issue: fire ALL halo pull loads up front (independent
        //      relaxed agent atomics; latency hides under A-phase) ----
        const ull* bb = strips + (size_t)(((t ^ 1) & 1) * NSHOT + s) * 4 * FSTRIDE;
        const unsigned want = (unsigned)t;
        const ull* qp0 = bb + (size_t)qg0 * 4;
        const ull* qp1 = bb + (size_t)qg1 * 4;
        ull ua0 = 0, ub0 = 0, uc0 = 0;
        ull ua1 = 0, ub1 = 0, uc1 = 0;
        if (hq0) { ua0 = aload(qp0); ub0 = aload(qp0 + 1); uc0 = aload(qp0 + 2); }
        if (hq1) { ua1 = aload(qp1); ub1 = aload(qp1 + 1); uc1 = aload(qp1 + 2); }

        // ---- A: velocity core (block-local; overlaps in-flight pulls) ----
        for (int i = tid; i < nCore; i += NTHR) {
            int r = i / cw, c = i - r * cw;
            doV(cy0 + r, cx0 + c, amp_t);
        }

        // ---- B-resolve: tag-check (spin only if neighbor is late) ----
        {
            auto resolve = [&](bool hv, int o, const ull* qp,
                               ull ua, ull ub, ull uc) {
                if (!hv) return;
                while ((unsigned)(ua >> 32) != want) {
                    __builtin_amdgcn_s_sleep(1); ua = aload(qp);
                }
                syyF[o] = __uint_as_float((unsigned)ua);
                while ((unsigned)(ub >> 32) != want) {
                    __builtin_amdgcn_s_sleep(1); ub = aload(qp + 1);
                }
                sxxF[o] = __uint_as_float((unsigned)ub);
                while ((unsigned)(uc >> 32) != want) {
                    __builtin_amdgcn_s_sleep(1); uc = aload(qp + 2);
                }
                sxyF[o] = __uint_as_float((unsigned)uc);
            };
            resolve(hq0, qo0, qp0, ua0, ub0, uc0);
            resolve(hq1, qo1, qp1, ua1, ub1, uc1);
        }
        __syncthreads();

        // ---- C: velocity ring (+2 redundant, needs the pulled halo) ----
        for (int i = tid; i < nRing; i += NTHR) {
            int y, x, j = i;
            if (j < nTop)           { y = vy0 + j / W2;     x = vx0 + j % W2; }
            else { j -= nTop;
            if (j < nBot)           { y = cy1 + j / W2;     x = vx0 + j % W2; }
            else { j -= nBot;
            if (j < nLeft)          { y = cy0 + j / leftW;  x = vx0 + j % leftW; }
            else { j -= nLeft;        y = cy0 + j / rightW; x = cx1 + j % rightW; } } }
            doV(y, x, amp_t);
        }
        __syncthreads();

        if (hasRec) out[recOff + t] = vyR[rvi][rvj];

        // ---- D1: boundary stress (depth<4), publish immediately (tag t+1) ----
        {
            ull* pb = strips + (size_t)((t & 1) * NSHOT + s) * 4 * FSTRIDE;
            const unsigned tag = (unsigned)(t + 1);
            const int midH = h - 8;
            const int nT4 = 4 * w, nB4 = 4 * w, nL4 = midH * 4;
            const int nD1 = nT4 + nB4 + 2 * nL4;
            for (int i = tid; i < nD1; i += NTHR) {
                int ly, lx, j = i;
                if (j < nT4)      { ly = j / w;           lx = j - (j / w) * w; }
                else { j -= nT4;
                if (j < nB4)      { ly = h - 4 + j / w;   lx = j - (j / w) * w; }
                else { j -= nB4;
                if (j < nL4)      { ly = 4 + (j >> 2);    lx = j & 3; }
                else { j -= nL4;    ly = 4 + (j >> 2);    lx = w - 4 + (j & 3); } } }
                doS(ly, lx, pb, tag, true);
            }
            // ---- D2: interior stress (off the inter-block critical path) ----
            const int w8 = w - 8, nD2 = midH * w8;
            for (int i = tid; i < nD2; i += NTHR) {
                int r = i / w8, c = i - r * w8;
                doS(4 + r, 4 + c, pb, 0u, false);
            }
        }
        __syncthreads();
    }
}

// ------------------------------ fallback path (R1, proven) ------------------

__global__ __launch_bounds__(256)
void vel_kernel(float* __restrict__ ws, const float* __restrict__ params,
                const float* __restrict__ bdec, const float* __restrict__ amps,
                const int* __restrict__ sloc, int t) {
    int x = blockIdx.x * 64 + threadIdx.x;
    int y = blockIdx.y * 4 + threadIdx.y;
    int s = blockIdx.z;
    if (x >= NXP) return;
    float* F = ws + (size_t)s * 13 * FSTRIDE;
    float* vy = F; float* vx = F + FSTRIDE;
    const float* syy = F + 2 * FSTRIDE;
    const float* sxx = F + 3 * FSTRIDE;
    const float* sxy = F + 4 * FSTRIDE;
    float* msyy_y = F + 9 * FSTRIDE;  float* msxy_x = F + 10 * FSTRIDE;
    float* msxy_y = F + 11 * FSTRIDE; float* msxx_x = F + 12 * FSTRIDE;
    float by = bdec[y], bx = bdec[NYP + x];
    int idx = y * PITCH + x;
    auto ldf2 = [&](const float* f, int yy, int xx) {
        return (yy >= 0 && yy < NYP && xx >= 0 && xx < NXP) ? f[yy * PITCH + xx] : 0.0f;
    };
    float buoy = params[3 * FSTRIDE + idx];
    float d, m;
    d = (C1C * (ldf2(syy,y+1,x) - ldf2(syy,y,x)) + C2C * (ldf2(syy,y+2,x) - ldf2(syy,y-1,x))) * RDX;
    m = by * msyy_y[idx] + (by - 1.0f) * d; msyy_y[idx] = m;
    float a1 = d + m;
    d = (C1C * (ldf2(sxy,y,x) - ldf2(sxy,y,x-1)) + C2C * (ldf2(sxy,y,x+1) - ldf2(sxy,y,x-2))) * RDX;
    m = bx * msxy_x[idx] + (bx - 1.0f) * d; msxy_x[idx] = m;
    float nvy = vy[idx] + DTC * buoy * (a1 + d + m);
    d = (C1C * (ldf2(sxy,y,x) - ldf2(sxy,y-1,x)) + C2C * (ldf2(sxy,y+1,x) - ldf2(sxy,y-2,x))) * RDX;
    m = by * msxy_y[idx] + (by - 1.0f) * d; msxy_y[idx] = m;
    float a2 = d + m;
    d = (C1C * (ldf2(sxx,y,x+1) - ldf2(sxx,y,x)) + C2C * (ldf2(sxx,y,x+2) - ldf2(sxx,y,x-1))) * RDX;
    m = bx * msxx_x[idx] + (bx - 1.0f) * d; msxx_x[idx] = m;
    float nvx = vx[idx] + DTC * buoy * (a2 + d + m);
    int sy = sloc[s * 2 + 0] + PML, sx = sloc[s * 2 + 1] + PML;
    if (y == sy && x == sx) nvy += amps[s * NT + t];
    vy[idx] = nvy; vx[idx] = nvx;
}

__global__ __launch_bounds__(256)
void str_kernel(float* __restrict__ ws, const float* __restrict__ params,
                const float* __restrict__ bdec, const int* __restrict__ rloc,
                float* __restrict__ out, int t) {
    int x = blockIdx.x * 64 + threadIdx.x;
    int y = blockIdx.y * 4 + threadIdx.y;
    int s = blockIdx.z;
    float* F = ws + (size_t)s * 13 * FSTRIDE;
    const float* vy = F; const float* vx = F + FSTRIDE;
    float* syy = F + 2 * FSTRIDE; float* sxx = F + 3 * FSTRIDE; float* sxy = F + 4 * FSTRIDE;
    float* mvyy = F + 5 * FSTRIDE; float* mvyx = F + 6 * FSTRIDE;
    float* mvxy = F + 7 * FSTRIDE; float* mvxx = F + 8 * FSTRIDE;
    if (blockIdx.x == 0 && blockIdx.y == 0) {
        int tid = threadIdx.y * 64 + threadIdx.x;
        if (tid < NREC) {
            int ry = rloc[(s * NREC + tid) * 2 + 0] + PML;
            int rx = rloc[(s * NREC + tid) * 2 + 1] + PML;
            out[(s * NREC + tid) * NT + t] = vy[ry * PITCH + rx];
        }
    }
    if (x >= NXP) return;
    auto ldf2 = [&](const float* f, int yy, int xx) {
        return (yy >= 0 && yy < NYP && xx >= 0 && xx < NXP) ? f[yy * PITCH + xx] : 0.0f;
    };
    float by = bdec[y], bx = bdec[NYP + x];
    int idx = y * PITCH + x;
    float lam = params[idx], lp2m = params[FSTRIDE + idx], muv = params[2 * FSTRIDE + idx];
    float d, m;
    d = (C1C * (ldf2(vy,y,x) - ldf2(vy,y-1,x)) + C2C * (ldf2(vy,y+1,x) - ldf2(vy,y-2,x))) * RDX;
    m = by * mvyy[idx] + (by - 1.0f) * d; mvyy[idx] = m;
    float dvy_dy = d + m;
    d = (C1C * (ldf2(vx,y,x) - ldf2(vx,y,x-1)) + C2C * (ldf2(vx,y,x+1) - ldf2(vx,y,x-2))) * RDX;
    m = bx * mvxx[idx] + (bx - 1.0f) * d; mvxx[idx] = m;
    float dvx_dx = d + m;
    syy[idx] += DTC * (lp2m * dvy_dy + lam * dvx_dx);
    sxx[idx] += DTC * (lp2m * dvx_dx + lam * dvy_dy);
    d = (C1C * (ldf2(vy,y,x+1) - ldf2(vy,y,x)) + C2C * (ldf2(vy,y,x+2) - ldf2(vy,y,x-1))) * RDX;
    m = bx * mvyx[idx] + (bx - 1.0f) * d; mvyx[idx] = m;
    float dvy_dx = d + m;
    d = (C1C * (ldf2(vx,y+1,x) - ldf2(vx,y,x)) + C2C * (ldf2(vx,y+2,x) - ldf2(vx,y-1,x))) * RDX;
    m = by * mvxy[idx] + (by - 1.0f) * d; mvxy[idx] = m;
    float dvx_dy = d + m;
    sxy[idx] += DTC * muv * (dvy_dx + dvx_dy);
}

// ----------------------------------------------------------------------------

extern "C" void kernel_launch(void* const* d_in, const int* in_sizes, int n_in,
                              void* d_out, int out_size, void* d_ws, size_t ws_size,
                              hipStream_t stream) {
    const float* lamb = (const float*)d_in[0];
    const float* mu   = (const float*)d_in[1];
    const float* buo  = (const float*)d_in[2];
    const float* amps = (const float*)d_in[3];
    const int*   sloc = (const int*)d_in[4];
    const int*   rloc = (const int*)d_in[5];
    float* out = (float*)d_out;

    float* wsf = (float*)d_ws;
    // layout: [strips: 16*FSTRIDE ull (2 parities x 2 shots x 4-ull cell records)]
    //         (persist path computes params/decay inline; region after strips
    //          unused there but kept in the `needed` check for layout parity)
    ull*   strips = (ull*)wsf;
    size_t needed = ((size_t)36 * FSTRIDE + NYP + NXP) * sizeof(float);

    if (ws_size >= needed) {
        (void)hipMemsetAsync(strips, 0, (size_t)16 * FSTRIDE * sizeof(ull), stream);
        void* args[] = {&strips, &lamb, &mu, &buo, &amps, &sloc, &rloc, &out};
        (void)hipLaunchCooperativeKernel((void*)persist6_kernel, dim3(NSHOT * TPS),
                                         dim3(NTHR), args, 0, stream);
    } else {
        dim3 pib(256, 1, 1), pig((NXP + 255) / 256, NYP, 1);
        float* statef = wsf + 64;
        float* paramf = wsf + 64 + (size_t)26 * FSTRIDE;
        float* bdecf  = wsf + 64 + (size_t)30 * FSTRIDE;
        (void)hipMemsetAsync(statef, 0, (size_t)26 * FSTRIDE * sizeof(float), stream);
        init_params_kernel<<<pig, pib, 0, stream>>>(lamb, mu, buo, paramf);
        init_decay_kernel<<<(NYP + NXP + 255) / 256, 256, 0, stream>>>(bdecf);
        dim3 blk(64, 4, 1), grd((NXP + 63) / 64, NYP / 4, NSHOT);
        for (int t = 0; t < NT; ++t) {
            vel_kernel<<<grd, blk, 0, stream>>>(statef, paramf, bdecf, amps, sloc, t);
            str_kernel<<<grd, blk, 0, stream>>>(statef, paramf, bdecf, rloc, out, t);
        }
    }
}

// Round 9
// 635.733 us; speedup vs baseline: 1.3355x; 1.2836x over previous
//
#include <hip/hip_runtime.h>

// ---------------------------------------------------------------------------
// Elastic 2D velocity-stress staggered FD + C-PML, 2 shots, 128 steps.
// Round 18: R15 base (776us, passed, 256 blocks = all CUs) + 2-WORD PACKED
// PUBLISH. Confirmed model (R15/R17 fit dur/step = x+c+s exactly): every 8B
// agent atomic store = one 32B fabric transaction (WRITE_SIZE == #stores*32B,
// verified twice); traffic term x ~= 4.5us/step dominates at R15 geometry.
// Only 129 tag values are used -> 16-bit tags suffice. New cell record:
//   word0 = [tag16 | sxx_hi16 | syy_f32], word1 = [tag16 | sxx_lo16 | sxy_f32]
// Each word individually atomic + individually tag-validated => protocol
// semantics identical to the proven 3-word scheme (zero-init = tag0 = step-0
// want with zero payload). sxx reconstructed bit-exactly. Stores/pulls per
// boundary cell 3 -> 2 (-33% transactions).
//  - R17 (big tiles): WRITE -31% exactly as predicted, but half CUs idle ->
//    compute doubled, net -2.5%. Reverted to 256-block geometry.
//  - R16 (reg-cache): LDS never binding, regressed, reverted.
// ---------------------------------------------------------------------------

typedef unsigned long long ull;

#define NYI   300
#define NXI   300
#define PML   20
#define NYP   340
#define NXP   340
#define NT    128
#define DXC   5.0f
#define DTC   0.001f
#define NSHOT 2
#define NREC  32
#define C1C   (9.0f / 8.0f)
#define C2C   (-1.0f / 24.0f)
#define RDX   (1.0f / 5.0f)

#define PITCH   344
#define FSTRIDE (NYP * PITCH)

// tile grid per shot: 8 x 16 tiles
#define TX 8
#define TY 16
#define TW 43
#define TH 22
#define MH 30
#define MW 52
#define VH 26
#define VW 48
#define IH 22
#define IW 44

#define NTHR 1024

__device__ __forceinline__ ull aload(const ull* p) {
    return __hip_atomic_load(p, __ATOMIC_RELAXED, __HIP_MEMORY_SCOPE_AGENT);
}
__device__ __forceinline__ void astore(ull* p, ull u) {
    __hip_atomic_store(p, u, __ATOMIC_RELAXED, __HIP_MEMORY_SCOPE_AGENT);
}
__device__ __forceinline__ float decay_at(int idx) {
    float fx = (float)idx;
    float lo = fminf(fmaxf(((float)PML - fx) / (float)PML, 0.0f), 1.0f);
    float hi = fminf(fmaxf((fx - (float)(NYP - 1 - PML)) / (float)PML, 0.0f), 1.0f);
    float mx = fmaxf(lo, hi);
    float d0 = 3.0f * 2000.0f / (2.0f * (float)PML * DXC) * logf(1.0f / 1e-6f);
    return expf(-d0 * mx * mx * DTC);
}
__device__ __forceinline__ int clampi(int v, int hi) {
    return v < 0 ? 0 : (v > hi ? hi : v);
}

__global__ void init_params_kernel(const float* __restrict__ lamb,
                                   const float* __restrict__ mu,
                                   const float* __restrict__ buo,
                                   float* __restrict__ params) {
    int x = blockIdx.x * blockDim.x + threadIdx.x;
    int y = blockIdx.y;
    if (x >= NXP || y >= NYP) return;
    int cy = y - PML; cy = cy < 0 ? 0 : (cy > NYI - 1 ? NYI - 1 : cy);
    int cx = x - PML; cx = cx < 0 ? 0 : (cx > NXI - 1 ? NXI - 1 : cx);
    float l = lamb[cy * NXI + cx];
    float m = mu[cy * NXI + cx];
    float b = buo[cy * NXI + cx];
    int idx = y * PITCH + x;
    params[0 * FSTRIDE + idx] = l;
    params[1 * FSTRIDE + idx] = l + 2.0f * m;
    params[2 * FSTRIDE + idx] = m;
    params[3 * FSTRIDE + idx] = b;
}

__global__ void init_decay_kernel(float* __restrict__ bdec) {
    int i = blockIdx.x * blockDim.x + threadIdx.x;
    if (i >= NYP + NXP) return;
    int idx = (i < NYP) ? i : i - NYP;
    bdec[i] = decay_at(idx);
}

__global__ __launch_bounds__(NTHR)
void persist6_kernel(ull* __restrict__ strips, const float* __restrict__ lamb,
                     const float* __restrict__ mu, const float* __restrict__ buo,
                     const float* __restrict__ amps,
                     const int* __restrict__ sloc, const int* __restrict__ rloc,
                     float* __restrict__ out) {
    __shared__ float syyR[MH][MW], sxxR[MH][MW], sxyR[MH][MW];
    __shared__ float vyR[VH][VW], vxR[VH][VW];
    __shared__ float mv0[VH][VW], mv1[VH][VW], mv2[VH][VW], mv3[VH][VW];
    __shared__ float ms0[IH][IW], ms1[IH][IW], ms2[IH][IW], ms3[IH][IW];
    __shared__ float buoL[VH][VW];
    __shared__ float lamL[IH][IW], lp2mL[IH][IW], muL[IH][IW];
    __shared__ float byL[VH], bxL[VW];

    const int tid = threadIdx.x;
    const int s = blockIdx.x >> 7, tile = blockIdx.x & 127;
    const int txi = tile & 7, tyi = tile >> 3;
    const int x0 = txi * TW, x1 = min(x0 + TW, NXP);
    const int y0 = tyi * TH, y1 = min(y0 + TH, NYP);
    const int w = x1 - x0, h = y1 - y0;

    // ---- zero LDS state; compute params/decay directly into LDS ----
    for (int i = tid; i < MH * MW; i += NTHR) {
        int r = i / MW, c = i - r * MW;
        syyR[r][c] = 0.0f; sxxR[r][c] = 0.0f; sxyR[r][c] = 0.0f;
    }
    for (int i = tid; i < VH * VW; i += NTHR) {
        int r = i / VW, c = i - r * VW;
        vyR[r][c] = 0.0f; vxR[r][c] = 0.0f;
        mv0[r][c] = 0.0f; mv1[r][c] = 0.0f; mv2[r][c] = 0.0f; mv3[r][c] = 0.0f;
        buoL[r][c] = 0.0f;
    }
    for (int i = tid; i < IH * IW; i += NTHR) {
        int r = i / IW, c = i - r * IW;
        ms0[r][c] = 0.0f; ms1[r][c] = 0.0f; ms2[r][c] = 0.0f; ms3[r][c] = 0.0f;
    }
    if (tid < VH) {
        int y = y0 - 2 + tid; y = min(max(y, 0), NYP - 1);
        byL[tid] = decay_at(y);
    } else if (tid >= 64 && tid < 64 + VW) {
        int i = tid - 64, x = x0 - 2 + i; x = min(max(x, 0), NXP - 1);
        bxL[i] = decay_at(x);
    }
    __syncthreads();
    {
        int ry0v = max(y0 - 2, 0), ry1v = min(y1 + 2, NYP);
        int rx0v = max(x0 - 2, 0), rx1v = min(x1 + 2, NXP);
        int rh = ry1v - ry0v, rw = rx1v - rx0v;
        for (int i = tid; i < rh * rw; i += NTHR) {
            int r = i / rw, c = i - r * rw;
            int y = ry0v + r, x = rx0v + c;
            int cy = clampi(y - PML, NYI - 1), cx = clampi(x - PML, NXI - 1);
            buoL[y - y0 + 2][x - x0 + 2] = buo[cy * NXI + cx];
        }
        for (int i = tid; i < h * w; i += NTHR) {
            int r = i / w, c = i - r * w;
            int cy = clampi(y0 + r - PML, NYI - 1), cx = clampi(x0 + c - PML, NXI - 1);
            float l = lamb[cy * NXI + cx];
            float m = mu[cy * NXI + cx];
            lamL[r][c] = l;
            lp2mL[r][c] = l + 2.0f * m;
            muL[r][c] = m;
        }
    }

    const int sy = sloc[s * 2 + 0] + PML;
    const int sx = sloc[s * 2 + 1] + PML;

    bool hasRec = false; int recOff = 0, rvi = 0, rvj = 0;
    if (tid < NSHOT * NREC) {
        int rs = tid >> 5, rr = tid & 31;
        if (rs == s) {
            int ry = rloc[(rs * NREC + rr) * 2 + 0] + PML;
            int rx = rloc[(rs * NREC + rr) * 2 + 1] + PML;
            if (ry >= y0 && ry < y1 && rx >= x0 && rx < x1) {
                hasRec = true; recOff = (rs * NREC + rr) * NT;
                rvi = ry - y0 + 2; rvj = rx - x0 + 2;
            }
        }
    }
    __syncthreads();

    // region geometry (identical to R6/R7, validated)
    const int vy0 = max(y0 - 2, 0), vy1 = min(y1 + 2, NYP);
    const int vx0 = max(x0 - 2, 0), vx1 = min(x1 + 2, NXP);
    const int cy0 = y0 + 2, cy1 = y1 - 2, cx0 = x0 + 2, cx1 = x1 - 2;
    const int cw = cx1 - cx0, ch = cy1 - cy0, nCore = cw * ch;
    const int W2 = vx1 - vx0;
    const int topH = cy0 - vy0, botH = vy1 - cy1;
    const int leftW = cx0 - vx0, rightW = vx1 - cx1;
    const int nTop = topH * W2, nBot = botH * W2;
    const int nLeft = ch * leftW, nRight = ch * rightW;
    const int nRing = nTop + nBot + nLeft + nRight;
    const int py0 = max(y0 - 4, 0), py1 = min(y1 + 4, NYP);
    const int px0 = max(x0 - 4, 0), px1 = min(x1 + 4, NXP);
    const int W4 = px1 - px0;
    const int ptH = y0 - py0, pbH = py1 - y1;
    const int plW = x0 - px0, prW = px1 - x1;
    const int nPT = ptH * W4, nPB = pbH * W4, nPL = h * plW, nPR = h * prW;
    const int nPull = nPT + nPB + nPL + nPR;

    // ---- hoisted pull-cell decode (time-invariant; nPull <= 584 < 1024) ----
    const bool hq0 = tid < nPull;
    const bool hq1 = tid + NTHR < nPull;   // always false at 1024, kept generic
    int qg0 = 0, qo0 = 0, qg1 = 0, qo1 = 0;
    {
        auto decode = [&](int j, int& g, int& o) {
            int y, x;
            if (j < nPT)            { y = py0 + j / W4;  x = px0 + j % W4; }
            else { j -= nPT;
            if (j < nPB)            { y = y1 + j / W4;   x = px0 + j % W4; }
            else { j -= nPB;
            if (j < nPL)            { y = y0 + j / plW;  x = px0 + j % plW; }
            else { j -= nPL;          y = y0 + j / prW;  x = x1 + j % prW; } } }
            g = y * PITCH + x;
            o = (y - y0 + 4) * MW + (x - x0 + 4);
        };
        if (hq0) decode(tid,        qg0, qo0);
        if (hq1) decode(tid + NTHR, qg1, qo1);
    }
    float* const syyF = &syyR[0][0];
    float* const sxxF = &sxxR[0][0];
    float* const sxyF = &sxyR[0][0];

    auto doV = [&](int y, int x, float amp) {
        int hy = y - y0 + 4, hx = x - x0 + 4;
        int vi = y - y0 + 2, vj = x - x0 + 2;
        float by = byL[vi], bx = bxL[vj];
        float d1 = (C1C * (syyR[hy + 1][hx] - syyR[hy][hx]) +
                    C2C * (syyR[hy + 2][hx] - syyR[hy - 1][hx])) * RDX;   // dpy(syy)
        float m1 = by * mv0[vi][vj] + (by - 1.0f) * d1; mv0[vi][vj] = m1;
        float d2 = (C1C * (sxyR[hy][hx] - sxyR[hy][hx - 1]) +
                    C2C * (sxyR[hy][hx + 1] - sxyR[hy][hx - 2])) * RDX;   // dmx(sxy)
        float m2 = bx * mv1[vi][vj] + (bx - 1.0f) * d2; mv1[vi][vj] = m2;
        float nvy = vyR[vi][vj] + DTC * buoL[vi][vj] * (d1 + m1 + d2 + m2);
        float d3 = (C1C * (sxyR[hy][hx] - sxyR[hy - 1][hx]) +
                    C2C * (sxyR[hy + 1][hx] - sxyR[hy - 2][hx])) * RDX;   // dmy(sxy)
        float m3 = by * mv2[vi][vj] + (by - 1.0f) * d3; mv2[vi][vj] = m3;
        float d4 = (C1C * (sxxR[hy][hx + 1] - sxxR[hy][hx]) +
                    C2C * (sxxR[hy][hx + 2] - sxxR[hy][hx - 1])) * RDX;   // dpx(sxx)
        float m4 = bx * mv3[vi][vj] + (bx - 1.0f) * d4; mv3[vi][vj] = m4;
        float nvx = vxR[vi][vj] + DTC * buoL[vi][vj] * (d3 + m3 + d4 + m4);
        if (y == sy && x == sx) nvy += amp;
        vyR[vi][vj] = nvy; vxR[vi][vj] = nvx;
    };

    auto doS = [&](int ly, int lx, ull* q, unsigned tag, bool pub) {
        int vi = ly + 2, vj = lx + 2;
        float by = byL[vi], bx = bxL[vj];
        float d, m;
        d = (C1C * (vyR[vi][vj] - vyR[vi - 1][vj]) +
             C2C * (vyR[vi + 1][vj] - vyR[vi - 2][vj])) * RDX;            // dmy(vy)
        m = by * ms0[ly][lx] + (by - 1.0f) * d; ms0[ly][lx] = m;
        float dvy_dy = d + m;
        d = (C1C * (vxR[vi][vj] - vxR[vi][vj - 1]) +
             C2C * (vxR[vi][vj + 1] - vxR[vi][vj - 2])) * RDX;            // dmx(vx)
        m = bx * ms1[ly][lx] + (bx - 1.0f) * d; ms1[ly][lx] = m;
        float dvx_dx = d + m;
        float nsyy = syyR[ly + 4][lx + 4] + DTC * (lp2mL[ly][lx] * dvy_dy + lamL[ly][lx] * dvx_dx);
        float nsxx = sxxR[ly + 4][lx + 4] + DTC * (lp2mL[ly][lx] * dvx_dx + lamL[ly][lx] * dvy_dy);
        d = (C1C * (vyR[vi][vj + 1] - vyR[vi][vj]) +
             C2C * (vyR[vi][vj + 2] - vyR[vi][vj - 1])) * RDX;            // dpx(vy)
        m = bx * ms2[ly][lx] + (bx - 1.0f) * d; ms2[ly][lx] = m;
        float dvy_dx = d + m;
        d = (C1C * (vxR[vi + 1][vj] - vxR[vi][vj]) +
             C2C * (vxR[vi + 2][vj] - vxR[vi - 1][vj])) * RDX;            // dpy(vx)
        m = by * ms3[ly][lx] + (by - 1.0f) * d; ms3[ly][lx] = m;
        float dvx_dy = d + m;
        float nsxy = sxyR[ly + 4][lx + 4] + DTC * muL[ly][lx] * (dvy_dx + dvx_dy);
        syyR[ly + 4][lx + 4] = nsyy;
        sxxR[ly + 4][lx + 4] = nsxx;
        sxyR[ly + 4][lx + 4] = nsxy;
        if (pub) {
            // 2-word packed publish: each word self-tagged with tag16.
            // word0 = [tag16 | sxx_hi16 | syy], word1 = [tag16 | sxx_lo16 | sxy]
            int gi = (y0 + ly) * PITCH + (x0 + lx);
            ull* c = q + (size_t)gi * 4;
            unsigned syyb = __float_as_uint(nsyy);
            unsigned sxxb = __float_as_uint(nsxx);
            unsigned sxyb = __float_as_uint(nsxy);
            ull t16 = (ull)(tag & 0xffffu) << 48;
            astore(c,     t16 | ((ull)(sxxb >> 16) << 32) | (ull)syyb);
            astore(c + 1, t16 | ((ull)(sxxb & 0xffffu) << 32) | (ull)sxyb);
        }
    };

    for (int t = 0; t < NT; ++t) {
        const float amp_t = amps[s * NT + t];

        // ---- B-issue: fire ALL halo pull loads up front (independent
        //      relaxed agent atomics; latency hides under A-phase) ----
        const ull* bb = strips + (size_t)(((t ^ 1) & 1) * NSHOT + s) * 4 * FSTRIDE;
        const unsigned want16 = (unsigned)t & 0xffffu;
        const ull* qp0 = bb + (size_t)qg0 * 4;
        const ull* qp1 = bb + (size_t)qg1 * 4;
        ull ua0 = 0, ub0 = 0;
        ull ua1 = 0, ub1 = 0;
        if (hq0) { ua0 = aload(qp0); ub0 = aload(qp0 + 1); }
        if (hq1) { ua1 = aload(qp1); ub1 = aload(qp1 + 1); }

        // ---- A: velocity core (block-local; overlaps in-flight pulls) ----
        for (int i = tid; i < nCore; i += NTHR) {
            int r = i / cw, c = i - r * cw;
            doV(cy0 + r, cx0 + c, amp_t);
        }

        // ---- B-resolve: tag-check both words (spin only if neighbor late);
        //      reconstruct sxx bit-exactly from the two 16-bit halves ----
        {
            auto resolve = [&](bool hv, int o, const ull* qp, ull ua, ull ub) {
                if (!hv) return;
                while ((unsigned)(ua >> 48) != want16) {
                    __builtin_amdgcn_s_sleep(1); ua = aload(qp);
                }
                while ((unsigned)(ub >> 48) != want16) {
                    __builtin_amdgcn_s_sleep(1); ub = aload(qp + 1);
                }
                syyF[o] = __uint_as_float((unsigned)(ua & 0xffffffffu));
                sxyF[o] = __uint_as_float((unsigned)(ub & 0xffffffffu));
                unsigned sxxb = (((unsigned)(ua >> 32) & 0xffffu) << 16) |
                                ((unsigned)(ub >> 32) & 0xffffu);
                sxxF[o] = __uint_as_float(sxxb);
            };
            resolve(hq0, qo0, qp0, ua0, ub0);
            resolve(hq1, qo1, qp1, ua1, ub1);
        }
        __syncthreads();

        // ---- C: velocity ring (+2 redundant, needs the pulled halo) ----
        for (int i = tid; i < nRing; i += NTHR) {
            int y, x, j = i;
            if (j < nTop)           { y = vy0 + j / W2;     x = vx0 + j % W2; }
            else { j -= nTop;
            if (j < nBot)           { y = cy1 + j / W2;     x = vx0 + j % W2; }
            else { j -= nBot;
            if (j < nLeft)          { y = cy0 + j / leftW;  x = vx0 + j % leftW; }
            else { j -= nLeft;        y = cy0 + j / rightW; x = cx1 + j % rightW; } } }
            doV(y, x, amp_t);
        }
        __syncthreads();

        if (hasRec) out[recOff + t] = vyR[rvi][rvj];

        // ---- D1: boundary stress (depth<4), publish immediately (tag t+1) ----
        {
            ull* pb = strips + (size_t)((t & 1) * NSHOT + s) * 4 * FSTRIDE;
            const unsigned tag = (unsigned)(t + 1);
            const int midH = h - 8;
            const int nT4 = 4 * w, nB4 = 4 * w, nL4 = midH * 4;
            const int nD1 = nT4 + nB4 + 2 * nL4;
            for (int i = tid; i < nD1; i += NTHR) {
                int ly, lx, j = i;
                if (j < nT4)      { ly = j / w;           lx = j - (j / w) * w; }
                else { j -= nT4;
                if (j < nB4)      { ly = h - 4 + j / w;   lx = j - (j / w) * w; }
                else { j -= nB4;
                if (j < nL4)      { ly = 4 + (j >> 2);    lx = j & 3; }
                else { j -= nL4;    ly = 4 + (j >> 2);    lx = w - 4 + (j & 3); } } }
                doS(ly, lx, pb, tag, true);
            }
            // ---- D2: interior stress (off the inter-block critical path) ----
            const int w8 = w - 8, nD2 = midH * w8;
            for (int i = tid; i < nD2; i += NTHR) {
                int r = i / w8, c = i - r * w8;
                doS(4 + r, 4 + c, pb, 0u, false);
            }
        }
        __syncthreads();
    }
}

// ------------------------------ fallback path (R1, proven) ------------------

__global__ __launch_bounds__(256)
void vel_kernel(float* __restrict__ ws, const float* __restrict__ params,
                const float* __restrict__ bdec, const float* __restrict__ amps,
                const int* __restrict__ sloc, int t) {
    int x = blockIdx.x * 64 + threadIdx.x;
    int y = blockIdx.y * 4 + threadIdx.y;
    int s = blockIdx.z;
    if (x >= NXP) return;
    float* F = ws + (size_t)s * 13 * FSTRIDE;
    float* vy = F; float* vx = F + FSTRIDE;
    const float* syy = F + 2 * FSTRIDE;
    const float* sxx = F + 3 * FSTRIDE;
    const float* sxy = F + 4 * FSTRIDE;
    float* msyy_y = F + 9 * FSTRIDE;  float* msxy_x = F + 10 * FSTRIDE;
    float* msxy_y = F + 11 * FSTRIDE; float* msxx_x = F + 12 * FSTRIDE;
    float by = bdec[y], bx = bdec[NYP + x];
    int idx = y * PITCH + x;
    auto ldf2 = [&](const float* f, int yy, int xx) {
        return (yy >= 0 && yy < NYP && xx >= 0 && xx < NXP) ? f[yy * PITCH + xx] : 0.0f;
    };
    float buoy = params[3 * FSTRIDE + idx];
    float d, m;
    d = (C1C * (ldf2(syy,y+1,x) - ldf2(syy,y,x)) + C2C * (ldf2(syy,y+2,x) - ldf2(syy,y-1,x))) * RDX;
    m = by * msyy_y[idx] + (by - 1.0f) * d; msyy_y[idx] = m;
    float a1 = d + m;
    d = (C1C * (ldf2(sxy,y,x) - ldf2(sxy,y,x-1)) + C2C * (ldf2(sxy,y,x+1) - ldf2(sxy,y,x-2))) * RDX;
    m = bx * msxy_x[idx] + (bx - 1.0f) * d; msxy_x[idx] = m;
    float nvy = vy[idx] + DTC * buoy * (a1 + d + m);
    d = (C1C * (ldf2(sxy,y,x) - ldf2(sxy,y-1,x)) + C2C * (ldf2(sxy,y+1,x) - ldf2(sxy,y-2,x))) * RDX;
    m = by * msxy_y[idx] + (by - 1.0f) * d; msxy_y[idx] = m;
    float a2 = d + m;
    d = (C1C * (ldf2(sxx,y,x+1) - ldf2(sxx,y,x)) + C2C * (ldf2(sxx,y,x+2) - ldf2(sxx,y,x-1))) * RDX;
    m = bx * msxx_x[idx] + (bx - 1.0f) * d; msxx_x[idx] = m;
    float nvx = vx[idx] + DTC * buoy * (a2 + d + m);
    int sy = sloc[s * 2 + 0] + PML, sx = sloc[s * 2 + 1] + PML;
    if (y == sy && x == sx) nvy += amps[s * NT + t];
    vy[idx] = nvy; vx[idx] = nvx;
}

__global__ __launch_bounds__(256)
void str_kernel(float* __restrict__ ws, const float* __restrict__ params,
                const float* __restrict__ bdec, const int* __restrict__ rloc,
                float* __restrict__ out, int t) {
    int x = blockIdx.x * 64 + threadIdx.x;
    int y = blockIdx.y * 4 + threadIdx.y;
    int s = blockIdx.z;
    float* F = ws + (size_t)s * 13 * FSTRIDE;
    const float* vy = F; const float* vx = F + FSTRIDE;
    float* syy = F + 2 * FSTRIDE; float* sxx = F + 3 * FSTRIDE; float* sxy = F + 4 * FSTRIDE;
    float* mvyy = F + 5 * FSTRIDE; float* mvyx = F + 6 * FSTRIDE;
    float* mvxy = F + 7 * FSTRIDE; float* mvxx = F + 8 * FSTRIDE;
    if (blockIdx.x == 0 && blockIdx.y == 0) {
        int tid = threadIdx.y * 64 + threadIdx.x;
        if (tid < NREC) {
            int ry = rloc[(s * NREC + tid) * 2 + 0] + PML;
            int rx = rloc[(s * NREC + tid) * 2 + 1] + PML;
            out[(s * NREC + tid) * NT + t] = vy[ry * PITCH + rx];
        }
    }
    if (x >= NXP) return;
    auto ldf2 = [&](const float* f, int yy, int xx) {
        return (yy >= 0 && yy < NYP && xx >= 0 && xx < NXP) ? f[yy * PITCH + xx] : 0.0f;
    };
    float by = bdec[y], bx = bdec[NYP + x];
    int idx = y * PITCH + x;
    float lam = params[idx], lp2m = params[FSTRIDE + idx], muv = params[2 * FSTRIDE + idx];
    float d, m;
    d = (C1C * (ldf2(vy,y,x) - ldf2(vy,y-1,x)) + C2C * (ldf2(vy,y+1,x) - ldf2(vy,y-2,x))) * RDX;
    m = by * mvyy[idx] + (by - 1.0f) * d; mvyy[idx] = m;
    float dvy_dy = d + m;
    d = (C1C * (ldf2(vx,y,x) - ldf2(vx,y,x-1)) + C2C * (ldf2(vx,y,x+1) - ldf2(vx,y,x-2))) * RDX;
    m = bx * mvxx[idx] + (bx - 1.0f) * d; mvxx[idx] = m;
    float dvx_dx = d + m;
    syy[idx] += DTC * (lp2m * dvy_dy + lam * dvx_dx);
    sxx[idx] += DTC * (lp2m * dvx_dx + lam * dvy_dy);
    d = (C1C * (ldf2(vy,y,x+1) - ldf2(vy,y,x)) + C2C * (ldf2(vy,y,x+2) - ldf2(vy,y,x-1))) * RDX;
    m = bx * mvyx[idx] + (bx - 1.0f) * d; mvyx[idx] = m;
    float dvy_dx = d + m;
    d = (C1C * (ldf2(vx,y+1,x) - ldf2(vx,y,x)) + C2C * (ldf2(vx,y+2,x) - ldf2(vx,y-1,x))) * RDX;
    m = by * mvxy[idx] + (by - 1.0f) * d; mvxy[idx] = m;
    float dvx_dy = d + m;
    sxy[idx] += DTC * muv * (dvy_dx + dvx_dy);
}

// ----------------------------------------------------------------------------

extern "C" void kernel_launch(void* const* d_in, const int* in_sizes, int n_in,
                              void* d_out, int out_size, void* d_ws, size_t ws_size,
                              hipStream_t stream) {
    const float* lamb = (const float*)d_in[0];
    const float* mu   = (const float*)d_in[1];
    const float* buo  = (const float*)d_in[2];
    const float* amps = (const float*)d_in[3];
    const int*   sloc = (const int*)d_in[4];
    const int*   rloc = (const int*)d_in[5];
    float* out = (float*)d_out;

    float* wsf = (float*)d_ws;
    // layout: [strips: 16*FSTRIDE ull (2 parities x 2 shots x 4-ull cell records)]
    //         (persist path computes params/decay inline; region after strips
    //          unused there but kept in the `needed` check for layout parity)
    ull*   strips = (ull*)wsf;
    size_t needed = ((size_t)36 * FSTRIDE + NYP + NXP) * sizeof(float);

    if (ws_size >= needed) {
        (void)hipMemsetAsync(strips, 0, (size_t)16 * FSTRIDE * sizeof(ull), stream);
        void* args[] = {&strips, &lamb, &mu, &buo, &amps, &sloc, &rloc, &out};
        (void)hipLaunchCooperativeKernel((void*)persist6_kernel, dim3(NSHOT * TX * TY),
                                         dim3(NTHR), args, 0, stream);
    } else {
        dim3 pib(256, 1, 1), pig((NXP + 255) / 256, NYP, 1);
        float* statef = wsf + 64;
        float* paramf = wsf + 64 + (size_t)26 * FSTRIDE;
        float* bdecf  = wsf + 64 + (size_t)30 * FSTRIDE;
        (void)hipMemsetAsync(statef, 0, (size_t)26 * FSTRIDE * sizeof(float), stream);
        init_params_kernel<<<pig, pib, 0, stream>>>(lamb, mu, buo, paramf);
        init_decay_kernel<<<(NYP + NXP + 255) / 256, 256, 0, stream>>>(bdecf);
        dim3 blk(64, 4, 1), grd((NXP + 63) / 64, NYP / 4, NSHOT);
        for (int t = 0; t < NT; ++t) {
            vel_kernel<<<grd, blk, 0, stream>>>(statef, paramf, bdecf, amps, sloc, t);
            str_kernel<<<grd, blk, 0, stream>>>(statef, paramf, bdecf, rloc, out, t);
        }
    }
}

// Round 10
// 479.443 us; speedup vs baseline: 1.7708x; 1.3260x over previous
//
#include <hip/hip_runtime.h>

// ---------------------------------------------------------------------------
// Elastic 2D velocity-stress staggered FD + C-PML, 2 shots, 128 steps.
// Round 19: R18 base (570us dispatch, passed) + 16B SINGLE-TRANSACTION
// exchange. Confirmed model (3 rounds of exact counter predictions): each 8B
// agent atomic = one un-combined 32B write-through transaction; dur/step =
// x*(transactions) + compute + sync. The R18 2-word cell record (each 8B half
// self-tagged: w0=[tag16|sxx_hi16|syy], w1=[tag16|sxx_lo16|sxy]) is published
// as ONE naturally-aligned global_store_dwordx4 sc0 sc1 and pulled as ONE
// global_load_dwordx4 sc0 sc1 (split issue/wait, "+v"-carried dependence).
// Per-word tag validation unchanged => protocol semantics identical even if
// halves applied separately. Transactions per boundary cell: 2 -> 1 each way.
//  - R18: packed 2-word publish; WRITE -33% and dur -27% exactly as modeled.
//  - R17: big tiles cut WRITE -31% but idled half the CUs; reverted.
//  - R16: reg-cache; LDS never binding; reverted.
// ---------------------------------------------------------------------------

typedef unsigned long long ull;
typedef __attribute__((ext_vector_type(4))) unsigned int uint4v;

#define NYI   300
#define NXI   300
#define PML   20
#define NYP   340
#define NXP   340
#define NT    128
#define DXC   5.0f
#define DTC   0.001f
#define NSHOT 2
#define NREC  32
#define C1C   (9.0f / 8.0f)
#define C2C   (-1.0f / 24.0f)
#define RDX   (1.0f / 5.0f)

#define PITCH   344
#define FSTRIDE (NYP * PITCH)

// tile grid per shot: 8 x 16 tiles
#define TX 8
#define TY 16
#define TW 43
#define TH 22
#define MH 30
#define MW 52
#define VH 26
#define VW 48
#define IH 22
#define IW 44

#define NTHR 1024

// 16B system-coherent store: one fabric transaction for a whole cell record.
__device__ __forceinline__ void cstore16(ull* p, ull w0, ull w1) {
    uint4v v;
    v.x = (unsigned)w0; v.y = (unsigned)(w0 >> 32);
    v.z = (unsigned)w1; v.w = (unsigned)(w1 >> 32);
    asm volatile("global_store_dwordx4 %0, %1, off sc0 sc1"
                 :: "v"(p), "v"(v) : "memory");
}
// 16B system-coherent load, issue-only (no wait): latency hides under compute.
__device__ __forceinline__ uint4v cload16_issue(const ull* p) {
    uint4v r;
    asm volatile("global_load_dwordx4 %0, %1, off sc0 sc1"
                 : "=v"(r) : "v"(p) : "memory");
    return r;
}
// Wait for the issued load; "+v" makes every later use depend on this asm.
__device__ __forceinline__ void cload16_wait(uint4v& r) {
    asm volatile("s_waitcnt vmcnt(0)" : "+v"(r) :: "memory");
}
// Combined load+wait for the spin path.
__device__ __forceinline__ uint4v cload16_sync(const ull* p) {
    uint4v r;
    asm volatile("global_load_dwordx4 %0, %1, off sc0 sc1\n\ts_waitcnt vmcnt(0)"
                 : "=v"(r) : "v"(p) : "memory");
    return r;
}

__device__ __forceinline__ float decay_at(int idx) {
    float fx = (float)idx;
    float lo = fminf(fmaxf(((float)PML - fx) / (float)PML, 0.0f), 1.0f);
    float hi = fminf(fmaxf((fx - (float)(NYP - 1 - PML)) / (float)PML, 0.0f), 1.0f);
    float mx = fmaxf(lo, hi);
    float d0 = 3.0f * 2000.0f / (2.0f * (float)PML * DXC) * logf(1.0f / 1e-6f);
    return expf(-d0 * mx * mx * DTC);
}
__device__ __forceinline__ int clampi(int v, int hi) {
    return v < 0 ? 0 : (v > hi ? hi : v);
}

__global__ void init_params_kernel(const float* __restrict__ lamb,
                                   const float* __restrict__ mu,
                                   const float* __restrict__ buo,
                                   float* __restrict__ params) {
    int x = blockIdx.x * blockDim.x + threadIdx.x;
    int y = blockIdx.y;
    if (x >= NXP || y >= NYP) return;
    int cy = y - PML; cy = cy < 0 ? 0 : (cy > NYI - 1 ? NYI - 1 : cy);
    int cx = x - PML; cx = cx < 0 ? 0 : (cx > NXI - 1 ? NXI - 1 : cx);
    float l = lamb[cy * NXI + cx];
    float m = mu[cy * NXI + cx];
    float b = buo[cy * NXI + cx];
    int idx = y * PITCH + x;
    params[0 * FSTRIDE + idx] = l;
    params[1 * FSTRIDE + idx] = l + 2.0f * m;
    params[2 * FSTRIDE + idx] = m;
    params[3 * FSTRIDE + idx] = b;
}

__global__ void init_decay_kernel(float* __restrict__ bdec) {
    int i = blockIdx.x * blockDim.x + threadIdx.x;
    if (i >= NYP + NXP) return;
    int idx = (i < NYP) ? i : i - NYP;
    bdec[i] = decay_at(idx);
}

__global__ __launch_bounds__(NTHR)
void persist6_kernel(ull* __restrict__ strips, const float* __restrict__ lamb,
                     const float* __restrict__ mu, const float* __restrict__ buo,
                     const float* __restrict__ amps,
                     const int* __restrict__ sloc, const int* __restrict__ rloc,
                     float* __restrict__ out) {
    __shared__ float syyR[MH][MW], sxxR[MH][MW], sxyR[MH][MW];
    __shared__ float vyR[VH][VW], vxR[VH][VW];
    __shared__ float mv0[VH][VW], mv1[VH][VW], mv2[VH][VW], mv3[VH][VW];
    __shared__ float ms0[IH][IW], ms1[IH][IW], ms2[IH][IW], ms3[IH][IW];
    __shared__ float buoL[VH][VW];
    __shared__ float lamL[IH][IW], lp2mL[IH][IW], muL[IH][IW];
    __shared__ float byL[VH], bxL[VW];

    const int tid = threadIdx.x;
    const int s = blockIdx.x >> 7, tile = blockIdx.x & 127;
    const int txi = tile & 7, tyi = tile >> 3;
    const int x0 = txi * TW, x1 = min(x0 + TW, NXP);
    const int y0 = tyi * TH, y1 = min(y0 + TH, NYP);
    const int w = x1 - x0, h = y1 - y0;

    // ---- zero LDS state; compute params/decay directly into LDS ----
    for (int i = tid; i < MH * MW; i += NTHR) {
        int r = i / MW, c = i - r * MW;
        syyR[r][c] = 0.0f; sxxR[r][c] = 0.0f; sxyR[r][c] = 0.0f;
    }
    for (int i = tid; i < VH * VW; i += NTHR) {
        int r = i / VW, c = i - r * VW;
        vyR[r][c] = 0.0f; vxR[r][c] = 0.0f;
        mv0[r][c] = 0.0f; mv1[r][c] = 0.0f; mv2[r][c] = 0.0f; mv3[r][c] = 0.0f;
        buoL[r][c] = 0.0f;
    }
    for (int i = tid; i < IH * IW; i += NTHR) {
        int r = i / IW, c = i - r * IW;
        ms0[r][c] = 0.0f; ms1[r][c] = 0.0f; ms2[r][c] = 0.0f; ms3[r][c] = 0.0f;
    }
    if (tid < VH) {
        int y = y0 - 2 + tid; y = min(max(y, 0), NYP - 1);
        byL[tid] = decay_at(y);
    } else if (tid >= 64 && tid < 64 + VW) {
        int i = tid - 64, x = x0 - 2 + i; x = min(max(x, 0), NXP - 1);
        bxL[i] = decay_at(x);
    }
    __syncthreads();
    {
        int ry0v = max(y0 - 2, 0), ry1v = min(y1 + 2, NYP);
        int rx0v = max(x0 - 2, 0), rx1v = min(x1 + 2, NXP);
        int rh = ry1v - ry0v, rw = rx1v - rx0v;
        for (int i = tid; i < rh * rw; i += NTHR) {
            int r = i / rw, c = i - r * rw;
            int y = ry0v + r, x = rx0v + c;
            int cy = clampi(y - PML, NYI - 1), cx = clampi(x - PML, NXI - 1);
            buoL[y - y0 + 2][x - x0 + 2] = buo[cy * NXI + cx];
        }
        for (int i = tid; i < h * w; i += NTHR) {
            int r = i / w, c = i - r * w;
            int cy = clampi(y0 + r - PML, NYI - 1), cx = clampi(x0 + c - PML, NXI - 1);
            float l = lamb[cy * NXI + cx];
            float m = mu[cy * NXI + cx];
            lamL[r][c] = l;
            lp2mL[r][c] = l + 2.0f * m;
            muL[r][c] = m;
        }
    }

    const int sy = sloc[s * 2 + 0] + PML;
    const int sx = sloc[s * 2 + 1] + PML;

    bool hasRec = false; int recOff = 0, rvi = 0, rvj = 0;
    if (tid < NSHOT * NREC) {
        int rs = tid >> 5, rr = tid & 31;
        if (rs == s) {
            int ry = rloc[(rs * NREC + rr) * 2 + 0] + PML;
            int rx = rloc[(rs * NREC + rr) * 2 + 1] + PML;
            if (ry >= y0 && ry < y1 && rx >= x0 && rx < x1) {
                hasRec = true; recOff = (rs * NREC + rr) * NT;
                rvi = ry - y0 + 2; rvj = rx - x0 + 2;
            }
        }
    }
    __syncthreads();

    // region geometry (identical to R6/R7, validated)
    const int vy0 = max(y0 - 2, 0), vy1 = min(y1 + 2, NYP);
    const int vx0 = max(x0 - 2, 0), vx1 = min(x1 + 2, NXP);
    const int cy0 = y0 + 2, cy1 = y1 - 2, cx0 = x0 + 2, cx1 = x1 - 2;
    const int cw = cx1 - cx0, ch = cy1 - cy0, nCore = cw * ch;
    const int W2 = vx1 - vx0;
    const int topH = cy0 - vy0, botH = vy1 - cy1;
    const int leftW = cx0 - vx0, rightW = vx1 - cx1;
    const int nTop = topH * W2, nBot = botH * W2;
    const int nLeft = ch * leftW, nRight = ch * rightW;
    const int nRing = nTop + nBot + nLeft + nRight;
    const int py0 = max(y0 - 4, 0), py1 = min(y1 + 4, NYP);
    const int px0 = max(x0 - 4, 0), px1 = min(x1 + 4, NXP);
    const int W4 = px1 - px0;
    const int ptH = y0 - py0, pbH = py1 - y1;
    const int plW = x0 - px0, prW = px1 - x1;
    const int nPT = ptH * W4, nPB = pbH * W4, nPL = h * plW, nPR = h * prW;
    const int nPull = nPT + nPB + nPL + nPR;

    // ---- hoisted pull-cell decode (time-invariant; nPull <= 584 < 1024) ----
    const bool hq0 = tid < nPull;
    int qg0 = 0, qo0 = 0;
    if (hq0) {
        int j = tid, y, x;
        if (j < nPT)            { y = py0 + j / W4;  x = px0 + j % W4; }
        else { j -= nPT;
        if (j < nPB)            { y = y1 + j / W4;   x = px0 + j % W4; }
        else { j -= nPB;
        if (j < nPL)            { y = y0 + j / plW;  x = px0 + j % plW; }
        else { j -= nPL;          y = y0 + j / prW;  x = x1 + j % prW; } } }
        qg0 = y * PITCH + x;
        qo0 = (y - y0 + 4) * MW + (x - x0 + 4);
    }
    float* const syyF = &syyR[0][0];
    float* const sxxF = &sxxR[0][0];
    float* const sxyF = &sxyR[0][0];

    auto doV = [&](int y, int x, float amp) {
        int hy = y - y0 + 4, hx = x - x0 + 4;
        int vi = y - y0 + 2, vj = x - x0 + 2;
        float by = byL[vi], bx = bxL[vj];
        float d1 = (C1C * (syyR[hy + 1][hx] - syyR[hy][hx]) +
                    C2C * (syyR[hy + 2][hx] - syyR[hy - 1][hx])) * RDX;   // dpy(syy)
        float m1 = by * mv0[vi][vj] + (by - 1.0f) * d1; mv0[vi][vj] = m1;
        float d2 = (C1C * (sxyR[hy][hx] - sxyR[hy][hx - 1]) +
                    C2C * (sxyR[hy][hx + 1] - sxyR[hy][hx - 2])) * RDX;   // dmx(sxy)
        float m2 = bx * mv1[vi][vj] + (bx - 1.0f) * d2; mv1[vi][vj] = m2;
        float nvy = vyR[vi][vj] + DTC * buoL[vi][vj] * (d1 + m1 + d2 + m2);
        float d3 = (C1C * (sxyR[hy][hx] - sxyR[hy - 1][hx]) +
                    C2C * (sxyR[hy + 1][hx] - sxyR[hy - 2][hx])) * RDX;   // dmy(sxy)
        float m3 = by * mv2[vi][vj] + (by - 1.0f) * d3; mv2[vi][vj] = m3;
        float d4 = (C1C * (sxxR[hy][hx + 1] - sxxR[hy][hx]) +
                    C2C * (sxxR[hy][hx + 2] - sxxR[hy][hx - 1])) * RDX;   // dpx(sxx)
        float m4 = bx * mv3[vi][vj] + (bx - 1.0f) * d4; mv3[vi][vj] = m4;
        float nvx = vxR[vi][vj] + DTC * buoL[vi][vj] * (d3 + m3 + d4 + m4);
        if (y == sy && x == sx) nvy += amp;
        vyR[vi][vj] = nvy; vxR[vi][vj] = nvx;
    };

    auto doS = [&](int ly, int lx, ull* q, unsigned tag, bool pub) {
        int vi = ly + 2, vj = lx + 2;
        float by = byL[vi], bx = bxL[vj];
        float d, m;
        d = (C1C * (vyR[vi][vj] - vyR[vi - 1][vj]) +
             C2C * (vyR[vi + 1][vj] - vyR[vi - 2][vj])) * RDX;            // dmy(vy)
        m = by * ms0[ly][lx] + (by - 1.0f) * d; ms0[ly][lx] = m;
        float dvy_dy = d + m;
        d = (C1C * (vxR[vi][vj] - vxR[vi][vj - 1]) +
             C2C * (vxR[vi][vj + 1] - vxR[vi][vj - 2])) * RDX;            // dmx(vx)
        m = bx * ms1[ly][lx] + (bx - 1.0f) * d; ms1[ly][lx] = m;
        float dvx_dx = d + m;
        float nsyy = syyR[ly + 4][lx + 4] + DTC * (lp2mL[ly][lx] * dvy_dy + lamL[ly][lx] * dvx_dx);
        float nsxx = sxxR[ly + 4][lx + 4] + DTC * (lp2mL[ly][lx] * dvx_dx + lamL[ly][lx] * dvy_dy);
        d = (C1C * (vyR[vi][vj + 1] - vyR[vi][vj]) +
             C2C * (vyR[vi][vj + 2] - vyR[vi][vj - 1])) * RDX;            // dpx(vy)
        m = bx * ms2[ly][lx] + (bx - 1.0f) * d; ms2[ly][lx] = m;
        float dvy_dx = d + m;
        d = (C1C * (vxR[vi + 1][vj] - vxR[vi][vj]) +
             C2C * (vxR[vi + 2][vj] - vxR[vi - 1][vj])) * RDX;            // dpy(vx)
        m = by * ms3[ly][lx] + (by - 1.0f) * d; ms3[ly][lx] = m;
        float dvx_dy = d + m;
        float nsxy = sxyR[ly + 4][lx + 4] + DTC * muL[ly][lx] * (dvy_dx + dvx_dy);
        syyR[ly + 4][lx + 4] = nsyy;
        sxxR[ly + 4][lx + 4] = nsxx;
        sxyR[ly + 4][lx + 4] = nsxy;
        if (pub) {
            // packed 2-word record (each 8B half self-tagged), ONE 16B store:
            // w0 = [tag16 | sxx_hi16 | syy], w1 = [tag16 | sxx_lo16 | sxy]
            int gi = (y0 + ly) * PITCH + (x0 + lx);
            ull* c = q + (size_t)gi * 4;
            unsigned syyb = __float_as_uint(nsyy);
            unsigned sxxb = __float_as_uint(nsxx);
            unsigned sxyb = __float_as_uint(nsxy);
            ull t16 = (ull)(tag & 0xffffu) << 48;
            ull w0 = t16 | ((ull)(sxxb >> 16) << 32) | (ull)syyb;
            ull w1 = t16 | ((ull)(sxxb & 0xffffu) << 32) | (ull)sxyb;
            cstore16(c, w0, w1);
        }
    };

    for (int t = 0; t < NT; ++t) {
        const float amp_t = amps[s * NT + t];

        // ---- B-issue: one 16B pull load per cell, fired up front; the
        //      latency hides under the A-phase compute ----
        const ull* bb = strips + (size_t)(((t ^ 1) & 1) * NSHOT + s) * 4 * FSTRIDE;
        const unsigned want16 = (unsigned)t & 0xffffu;
        const ull* qp0 = bb + (size_t)qg0 * 4;
        uint4v r0;
        if (hq0) r0 = cload16_issue(qp0);

        // ---- A: velocity core (block-local; overlaps in-flight pull) ----
        for (int i = tid; i < nCore; i += NTHR) {
            int r = i / cw, c = i - r * cw;
            doV(cy0 + r, cx0 + c, amp_t);
        }

        // ---- B-resolve: wait, tag-check both self-tagged halves, spin only
        //      if the neighbor is late; reconstruct sxx bit-exactly ----
        if (hq0) {
            cload16_wait(r0);
            while (((r0.y >> 16) != want16) || ((r0.w >> 16) != want16)) {
                __builtin_amdgcn_s_sleep(1);
                r0 = cload16_sync(qp0);
            }
            syyF[qo0] = __uint_as_float(r0.x);
            sxyF[qo0] = __uint_as_float(r0.z);
            sxxF[qo0] = __uint_as_float(((r0.y & 0xffffu) << 16) | (r0.w & 0xffffu));
        }
        __syncthreads();

        // ---- C: velocity ring (+2 redundant, needs the pulled halo) ----
        for (int i = tid; i < nRing; i += NTHR) {
            int y, x, j = i;
            if (j < nTop)           { y = vy0 + j / W2;     x = vx0 + j % W2; }
            else { j -= nTop;
            if (j < nBot)           { y = cy1 + j / W2;     x = vx0 + j % W2; }
            else { j -= nBot;
            if (j < nLeft)          { y = cy0 + j / leftW;  x = vx0 + j % leftW; }
            else { j -= nLeft;        y = cy0 + j / rightW; x = cx1 + j % rightW; } } }
            doV(y, x, amp_t);
        }
        __syncthreads();

        if (hasRec) out[recOff + t] = vyR[rvi][rvj];

        // ---- D1: boundary stress (depth<4), publish immediately (tag t+1) ----
        {
            ull* pb = strips + (size_t)((t & 1) * NSHOT + s) * 4 * FSTRIDE;
            const unsigned tag = (unsigned)(t + 1);
            const int midH = h - 8;
            const int nT4 = 4 * w, nB4 = 4 * w, nL4 = midH * 4;
            const int nD1 = nT4 + nB4 + 2 * nL4;
            for (int i = tid; i < nD1; i += NTHR) {
                int ly, lx, j = i;
                if (j < nT4)      { ly = j / w;           lx = j - (j / w) * w; }
                else { j -= nT4;
                if (j < nB4)      { ly = h - 4 + j / w;   lx = j - (j / w) * w; }
                else { j -= nB4;
                if (j < nL4)      { ly = 4 + (j >> 2);    lx = j & 3; }
                else { j -= nL4;    ly = 4 + (j >> 2);    lx = w - 4 + (j & 3); } } }
                doS(ly, lx, pb, tag, true);
            }
            // ---- D2: interior stress (off the inter-block critical path) ----
            const int w8 = w - 8, nD2 = midH * w8;
            for (int i = tid; i < nD2; i += NTHR) {
                int r = i / w8, c = i - r * w8;
                doS(4 + r, 4 + c, pb, 0u, false);
            }
        }
        __syncthreads();
    }
}

// ------------------------------ fallback path (R1, proven) ------------------

__global__ __launch_bounds__(256)
void vel_kernel(float* __restrict__ ws, const float* __restrict__ params,
                const float* __restrict__ bdec, const float* __restrict__ amps,
                const int* __restrict__ sloc, int t) {
    int x = blockIdx.x * 64 + threadIdx.x;
    int y = blockIdx.y * 4 + threadIdx.y;
    int s = blockIdx.z;
    if (x >= NXP) return;
    float* F = ws + (size_t)s * 13 * FSTRIDE;
    float* vy = F; float* vx = F + FSTRIDE;
    const float* syy = F + 2 * FSTRIDE;
    const float* sxx = F + 3 * FSTRIDE;
    const float* sxy = F + 4 * FSTRIDE;
    float* msyy_y = F + 9 * FSTRIDE;  float* msxy_x = F + 10 * FSTRIDE;
    float* msxy_y = F + 11 * FSTRIDE; float* msxx_x = F + 12 * FSTRIDE;
    float by = bdec[y], bx = bdec[NYP + x];
    int idx = y * PITCH + x;
    auto ldf2 = [&](const float* f, int yy, int xx) {
        return (yy >= 0 && yy < NYP && xx >= 0 && xx < NXP) ? f[yy * PITCH + xx] : 0.0f;
    };
    float buoy = params[3 * FSTRIDE + idx];
    float d, m;
    d = (C1C * (ldf2(syy,y+1,x) - ldf2(syy,y,x)) + C2C * (ldf2(syy,y+2,x) - ldf2(syy,y-1,x))) * RDX;
    m = by * msyy_y[idx] + (by - 1.0f) * d; msyy_y[idx] = m;
    float a1 = d + m;
    d = (C1C * (ldf2(sxy,y,x) - ldf2(sxy,y,x-1)) + C2C * (ldf2(sxy,y,x+1) - ldf2(sxy,y,x-2))) * RDX;
    m = bx * msxy_x[idx] + (bx - 1.0f) * d; msxy_x[idx] = m;
    float nvy = vy[idx] + DTC * buoy * (a1 + d + m);
    d = (C1C * (ldf2(sxy,y,x) - ldf2(sxy,y-1,x)) + C2C * (ldf2(sxy,y+1,x) - ldf2(sxy,y-2,x))) * RDX;
    m = by * msxy_y[idx] + (by - 1.0f) * d; msxy_y[idx] = m;
    float a2 = d + m;
    d = (C1C * (ldf2(sxx,y,x+1) - ldf2(sxx,y,x)) + C2C * (ldf2(sxx,y,x+2) - ldf2(sxx,y,x-1))) * RDX;
    m = bx * msxx_x[idx] + (bx - 1.0f) * d; msxx_x[idx] = m;
    float nvx = vx[idx] + DTC * buoy * (a2 + d + m);
    int sy = sloc[s * 2 + 0] + PML, sx = sloc[s * 2 + 1] + PML;
    if (y == sy && x == sx) nvy += amps[s * NT + t];
    vy[idx] = nvy; vx[idx] = nvx;
}

__global__ __launch_bounds__(256)
void str_kernel(float* __restrict__ ws, const float* __restrict__ params,
                const float* __restrict__ bdec, const int* __restrict__ rloc,
                float* __restrict__ out, int t) {
    int x = blockIdx.x * 64 + threadIdx.x;
    int y = blockIdx.y * 4 + threadIdx.y;
    int s = blockIdx.z;
    float* F = ws + (size_t)s * 13 * FSTRIDE;
    const float* vy = F; const float* vx = F + FSTRIDE;
    float* syy = F + 2 * FSTRIDE; float* sxx = F + 3 * FSTRIDE; float* sxy = F + 4 * FSTRIDE;
    float* mvyy = F + 5 * FSTRIDE; float* mvyx = F + 6 * FSTRIDE;
    float* mvxy = F + 7 * FSTRIDE; float* mvxx = F + 8 * FSTRIDE;
    if (blockIdx.x == 0 && blockIdx.y == 0) {
        int tid = threadIdx.y * 64 + threadIdx.x;
        if (tid < NREC) {
            int ry = rloc[(s * NREC + tid) * 2 + 0] + PML;
            int rx = rloc[(s * NREC + tid) * 2 + 1] + PML;
            out[(s * NREC + tid) * NT + t] = vy[ry * PITCH + rx];
        }
    }
    if (x >= NXP) return;
    auto ldf2 = [&](const float* f, int yy, int xx) {
        return (yy >= 0 && yy < NYP && xx >= 0 && xx < NXP) ? f[yy * PITCH + xx] : 0.0f;
    };
    float by = bdec[y], bx = bdec[NYP + x];
    int idx = y * PITCH + x;
    float lam = params[idx], lp2m = params[FSTRIDE + idx], muv = params[2 * FSTRIDE + idx];
    float d, m;
    d = (C1C * (ldf2(vy,y,x) - ldf2(vy,y-1,x)) + C2C * (ldf2(vy,y+1,x) - ldf2(vy,y-2,x))) * RDX;
    m = by * mvyy[idx] + (by - 1.0f) * d; mvyy[idx] = m;
    float dvy_dy = d + m;
    d = (C1C * (ldf2(vx,y,x) - ldf2(vx,y,x-1)) + C2C * (ldf2(vx,y,x+1) - ldf2(vx,y,x-2))) * RDX;
    m = bx * mvxx[idx] + (bx - 1.0f) * d; mvxx[idx] = m;
    float dvx_dx = d + m;
    syy[idx] += DTC * (lp2m * dvy_dy + lam * dvx_dx);
    sxx[idx] += DTC * (lp2m * dvx_dx + lam * dvy_dy);
    d = (C1C * (ldf2(vy,y,x+1) - ldf2(vy,y,x)) + C2C * (ldf2(vy,y,x+2) - ldf2(vy,y,x-1))) * RDX;
    m = bx * mvyx[idx] + (bx - 1.0f) * d; mvyx[idx] = m;
    float dvy_dx = d + m;
    d = (C1C * (ldf2(vx,y+1,x) - ldf2(vx,y,x)) + C2C * (ldf2(vx,y+2,x) - ldf2(vx,y-1,x))) * RDX;
    m = by * mvxy[idx] + (by - 1.0f) * d; mvxy[idx] = m;
    float dvx_dy = d + m;
    sxy[idx] += DTC * muv * (dvy_dx + dvx_dy);
}

// ----------------------------------------------------------------------------

extern "C" void kernel_launch(void* const* d_in, const int* in_sizes, int n_in,
                              void* d_out, int out_size, void* d_ws, size_t ws_size,
                              hipStream_t stream) {
    const float* lamb = (const float*)d_in[0];
    const float* mu   = (const float*)d_in[1];
    const float* buo  = (const float*)d_in[2];
    const float* amps = (const float*)d_in[3];
    const int*   sloc = (const int*)d_in[4];
    const int*   rloc = (const int*)d_in[5];
    float* out = (float*)d_out;

    float* wsf = (float*)d_ws;
    // layout: [strips: 16*FSTRIDE ull (2 parities x 2 shots x 4-ull cell records)]
    //         (persist path computes params/decay inline; region after strips
    //          unused there but kept in the `needed` check for layout parity)
    ull*   strips = (ull*)wsf;
    size_t needed = ((size_t)36 * FSTRIDE + NYP + NXP) * sizeof(float);

    if (ws_size >= needed) {
        (void)hipMemsetAsync(strips, 0, (size_t)16 * FSTRIDE * sizeof(ull), stream);
        void* args[] = {&strips, &lamb, &mu, &buo, &amps, &sloc, &rloc, &out};
        (void)hipLaunchCooperativeKernel((void*)persist6_kernel, dim3(NSHOT * TX * TY),
                                         dim3(NTHR), args, 0, stream);
    } else {
        dim3 pib(256, 1, 1), pig((NXP + 255) / 256, NYP, 1);
        float* statef = wsf + 64;
        float* paramf = wsf + 64 + (size_t)26 * FSTRIDE;
        float* bdecf  = wsf + 64 + (size_t)30 * FSTRIDE;
        (void)hipMemsetAsync(statef, 0, (size_t)26 * FSTRIDE * sizeof(float), stream);
        init_params_kernel<<<pig, pib, 0, stream>>>(lamb, mu, buo, paramf);
        init_decay_kernel<<<(NYP + NXP + 255) / 256, 256, 0, stream>>>(bdecf);
        dim3 blk(64, 4, 1), grd((NXP + 63) / 64, NYP / 4, NSHOT);
        for (int t = 0; t < NT; ++t) {
            vel_kernel<<<grd, blk, 0, stream>>>(statef, paramf, bdecf, amps, sloc, t);
            str_kernel<<<grd, blk, 0, stream>>>(statef, paramf, bdecf, rloc, out, t);
        }
    }
}

// Round 11
// 438.306 us; speedup vs baseline: 1.9370x; 1.0939x over previous
//
#include <hip/hip_runtime.h>

// ---------------------------------------------------------------------------
// Elastic 2D velocity-stress staggered FD + C-PML, 2 shots, 128 steps.
// Round 20: R19 base (402us dispatch, passed) + 16B-STRIDE PACKED RECORDS.
// Model (4 rounds of exact WRITE_SIZE predictions): cost == write-through
// transaction count; R19's 32B-stride records waste half of every 32B sector
// (16B payload per transaction, no cross-lane merge possible). Packing cell
// records at 16B stride makes adjacent lanes' global_store_dwordx4 in ONE
// wave instruction CONTIGUOUS -> intra-wave coalescing into full 32B/64B
// transactions (what failed before was combining across separate
// instructions). Record encoding unchanged (2 self-tagged 8B words:
// w0=[tag16|sxx_hi16|syy], w1=[tag16|sxx_lo16|sxy]); only strip addressing
// changes: record stride 4 -> 2 ulls, strips 16 -> 8 FSTRIDE ulls.
// Decisive counter: WRITE_SIZE ~456.7e3 -> ~230e3 KB if coalescing applies.
//  - R19: one 16B store/cell; WRITE halved, dur 570->402 as modeled.
//  - R18: packed 2-word publish; WRITE -33%, dur -27% as modeled.
// ---------------------------------------------------------------------------

typedef unsigned long long ull;
typedef __attribute__((ext_vector_type(4))) unsigned int uint4v;

#define NYI   300
#define NXI   300
#define PML   20
#define NYP   340
#define NXP   340
#define NT    128
#define DXC   5.0f
#define DTC   0.001f
#define NSHOT 2
#define NREC  32
#define C1C   (9.0f / 8.0f)
#define C2C   (-1.0f / 24.0f)
#define RDX   (1.0f / 5.0f)

#define PITCH   344
#define FSTRIDE (NYP * PITCH)
#define RECU    2            /* ulls per cell record (16B, packed) */

// tile grid per shot: 8 x 16 tiles
#define TX 8
#define TY 16
#define TW 43
#define TH 22
#define MH 30
#define MW 52
#define VH 26
#define VW 48
#define IH 22
#define IW 44

#define NTHR 1024

// 16B system-coherent store: one fabric transaction per cell record; with
// 16B-stride records adjacent lanes are contiguous -> intra-wave coalescing.
__device__ __forceinline__ void cstore16(ull* p, ull w0, ull w1) {
    uint4v v;
    v.x = (unsigned)w0; v.y = (unsigned)(w0 >> 32);
    v.z = (unsigned)w1; v.w = (unsigned)(w1 >> 32);
    asm volatile("global_store_dwordx4 %0, %1, off sc0 sc1"
                 :: "v"(p), "v"(v) : "memory");
}
// 16B system-coherent load, issue-only (no wait): latency hides under compute.
__device__ __forceinline__ uint4v cload16_issue(const ull* p) {
    uint4v r;
    asm volatile("global_load_dwordx4 %0, %1, off sc0 sc1"
                 : "=v"(r) : "v"(p) : "memory");
    return r;
}
// Wait for the issued load; "+v" makes every later use depend on this asm.
__device__ __forceinline__ void cload16_wait(uint4v& r) {
    asm volatile("s_waitcnt vmcnt(0)" : "+v"(r) :: "memory");
}
// Combined load+wait for the spin path.
__device__ __forceinline__ uint4v cload16_sync(const ull* p) {
    uint4v r;
    asm volatile("global_load_dwordx4 %0, %1, off sc0 sc1\n\ts_waitcnt vmcnt(0)"
                 : "=v"(r) : "v"(p) : "memory");
    return r;
}

__device__ __forceinline__ float decay_at(int idx) {
    float fx = (float)idx;
    float lo = fminf(fmaxf(((float)PML - fx) / (float)PML, 0.0f), 1.0f);
    float hi = fminf(fmaxf((fx - (float)(NYP - 1 - PML)) / (float)PML, 0.0f), 1.0f);
    float mx = fmaxf(lo, hi);
    float d0 = 3.0f * 2000.0f / (2.0f * (float)PML * DXC) * logf(1.0f / 1e-6f);
    return expf(-d0 * mx * mx * DTC);
}
__device__ __forceinline__ int clampi(int v, int hi) {
    return v < 0 ? 0 : (v > hi ? hi : v);
}

__global__ void init_params_kernel(const float* __restrict__ lamb,
                                   const float* __restrict__ mu,
                                   const float* __restrict__ buo,
                                   float* __restrict__ params) {
    int x = blockIdx.x * blockDim.x + threadIdx.x;
    int y = blockIdx.y;
    if (x >= NXP || y >= NYP) return;
    int cy = y - PML; cy = cy < 0 ? 0 : (cy > NYI - 1 ? NYI - 1 : cy);
    int cx = x - PML; cx = cx < 0 ? 0 : (cx > NXI - 1 ? NXI - 1 : cx);
    float l = lamb[cy * NXI + cx];
    float m = mu[cy * NXI + cx];
    float b = buo[cy * NXI + cx];
    int idx = y * PITCH + x;
    params[0 * FSTRIDE + idx] = l;
    params[1 * FSTRIDE + idx] = l + 2.0f * m;
    params[2 * FSTRIDE + idx] = m;
    params[3 * FSTRIDE + idx] = b;
}

__global__ void init_decay_kernel(float* __restrict__ bdec) {
    int i = blockIdx.x * blockDim.x + threadIdx.x;
    if (i >= NYP + NXP) return;
    int idx = (i < NYP) ? i : i - NYP;
    bdec[i] = decay_at(idx);
}

__global__ __launch_bounds__(NTHR)
void persist6_kernel(ull* __restrict__ strips, const float* __restrict__ lamb,
                     const float* __restrict__ mu, const float* __restrict__ buo,
                     const float* __restrict__ amps,
                     const int* __restrict__ sloc, const int* __restrict__ rloc,
                     float* __restrict__ out) {
    __shared__ float syyR[MH][MW], sxxR[MH][MW], sxyR[MH][MW];
    __shared__ float vyR[VH][VW], vxR[VH][VW];
    __shared__ float mv0[VH][VW], mv1[VH][VW], mv2[VH][VW], mv3[VH][VW];
    __shared__ float ms0[IH][IW], ms1[IH][IW], ms2[IH][IW], ms3[IH][IW];
    __shared__ float buoL[VH][VW];
    __shared__ float lamL[IH][IW], lp2mL[IH][IW], muL[IH][IW];
    __shared__ float byL[VH], bxL[VW];

    const int tid = threadIdx.x;
    const int s = blockIdx.x >> 7, tile = blockIdx.x & 127;
    const int txi = tile & 7, tyi = tile >> 3;
    const int x0 = txi * TW, x1 = min(x0 + TW, NXP);
    const int y0 = tyi * TH, y1 = min(y0 + TH, NYP);
    const int w = x1 - x0, h = y1 - y0;

    // ---- zero LDS state; compute params/decay directly into LDS ----
    for (int i = tid; i < MH * MW; i += NTHR) {
        int r = i / MW, c = i - r * MW;
        syyR[r][c] = 0.0f; sxxR[r][c] = 0.0f; sxyR[r][c] = 0.0f;
    }
    for (int i = tid; i < VH * VW; i += NTHR) {
        int r = i / VW, c = i - r * VW;
        vyR[r][c] = 0.0f; vxR[r][c] = 0.0f;
        mv0[r][c] = 0.0f; mv1[r][c] = 0.0f; mv2[r][c] = 0.0f; mv3[r][c] = 0.0f;
        buoL[r][c] = 0.0f;
    }
    for (int i = tid; i < IH * IW; i += NTHR) {
        int r = i / IW, c = i - r * IW;
        ms0[r][c] = 0.0f; ms1[r][c] = 0.0f; ms2[r][c] = 0.0f; ms3[r][c] = 0.0f;
    }
    if (tid < VH) {
        int y = y0 - 2 + tid; y = min(max(y, 0), NYP - 1);
        byL[tid] = decay_at(y);
    } else if (tid >= 64 && tid < 64 + VW) {
        int i = tid - 64, x = x0 - 2 + i; x = min(max(x, 0), NXP - 1);
        bxL[i] = decay_at(x);
    }
    __syncthreads();
    {
        int ry0v = max(y0 - 2, 0), ry1v = min(y1 + 2, NYP);
        int rx0v = max(x0 - 2, 0), rx1v = min(x1 + 2, NXP);
        int rh = ry1v - ry0v, rw = rx1v - rx0v;
        for (int i = tid; i < rh * rw; i += NTHR) {
            int r = i / rw, c = i - r * rw;
            int y = ry0v + r, x = rx0v + c;
            int cy = clampi(y - PML, NYI - 1), cx = clampi(x - PML, NXI - 1);
            buoL[y - y0 + 2][x - x0 + 2] = buo[cy * NXI + cx];
        }
        for (int i = tid; i < h * w; i += NTHR) {
            int r = i / w, c = i - r * w;
            int cy = clampi(y0 + r - PML, NYI - 1), cx = clampi(x0 + c - PML, NXI - 1);
            float l = lamb[cy * NXI + cx];
            float m = mu[cy * NXI + cx];
            lamL[r][c] = l;
            lp2mL[r][c] = l + 2.0f * m;
            muL[r][c] = m;
        }
    }

    const int sy = sloc[s * 2 + 0] + PML;
    const int sx = sloc[s * 2 + 1] + PML;

    bool hasRec = false; int recOff = 0, rvi = 0, rvj = 0;
    if (tid < NSHOT * NREC) {
        int rs = tid >> 5, rr = tid & 31;
        if (rs == s) {
            int ry = rloc[(rs * NREC + rr) * 2 + 0] + PML;
            int rx = rloc[(rs * NREC + rr) * 2 + 1] + PML;
            if (ry >= y0 && ry < y1 && rx >= x0 && rx < x1) {
                hasRec = true; recOff = (rs * NREC + rr) * NT;
                rvi = ry - y0 + 2; rvj = rx - x0 + 2;
            }
        }
    }
    __syncthreads();

    // region geometry (identical to R6/R7, validated)
    const int vy0 = max(y0 - 2, 0), vy1 = min(y1 + 2, NYP);
    const int vx0 = max(x0 - 2, 0), vx1 = min(x1 + 2, NXP);
    const int cy0 = y0 + 2, cy1 = y1 - 2, cx0 = x0 + 2, cx1 = x1 - 2;
    const int cw = cx1 - cx0, ch = cy1 - cy0, nCore = cw * ch;
    const int W2 = vx1 - vx0;
    const int topH = cy0 - vy0, botH = vy1 - cy1;
    const int leftW = cx0 - vx0, rightW = vx1 - cx1;
    const int nTop = topH * W2, nBot = botH * W2;
    const int nLeft = ch * leftW, nRight = ch * rightW;
    const int nRing = nTop + nBot + nLeft + nRight;
    const int py0 = max(y0 - 4, 0), py1 = min(y1 + 4, NYP);
    const int px0 = max(x0 - 4, 0), px1 = min(x1 + 4, NXP);
    const int W4 = px1 - px0;
    const int ptH = y0 - py0, pbH = py1 - y1;
    const int plW = x0 - px0, prW = px1 - x1;
    const int nPT = ptH * W4, nPB = pbH * W4, nPL = h * plW, nPR = h * prW;
    const int nPull = nPT + nPB + nPL + nPR;

    // ---- hoisted pull-cell decode (time-invariant; nPull <= 584 < 1024) ----
    const bool hq0 = tid < nPull;
    int qg0 = 0, qo0 = 0;
    if (hq0) {
        int j = tid, y, x;
        if (j < nPT)            { y = py0 + j / W4;  x = px0 + j % W4; }
        else { j -= nPT;
        if (j < nPB)            { y = y1 + j / W4;   x = px0 + j % W4; }
        else { j -= nPB;
        if (j < nPL)            { y = y0 + j / plW;  x = px0 + j % plW; }
        else { j -= nPL;          y = y0 + j / prW;  x = x1 + j % prW; } } }
        qg0 = y * PITCH + x;
        qo0 = (y - y0 + 4) * MW + (x - x0 + 4);
    }
    float* const syyF = &syyR[0][0];
    float* const sxxF = &sxxR[0][0];
    float* const sxyF = &sxyR[0][0];

    auto doV = [&](int y, int x, float amp) {
        int hy = y - y0 + 4, hx = x - x0 + 4;
        int vi = y - y0 + 2, vj = x - x0 + 2;
        float by = byL[vi], bx = bxL[vj];
        float d1 = (C1C * (syyR[hy + 1][hx] - syyR[hy][hx]) +
                    C2C * (syyR[hy + 2][hx] - syyR[hy - 1][hx])) * RDX;   // dpy(syy)
        float m1 = by * mv0[vi][vj] + (by - 1.0f) * d1; mv0[vi][vj] = m1;
        float d2 = (C1C * (sxyR[hy][hx] - sxyR[hy][hx - 1]) +
                    C2C * (sxyR[hy][hx + 1] - sxyR[hy][hx - 2])) * RDX;   // dmx(sxy)
        float m2 = bx * mv1[vi][vj] + (bx - 1.0f) * d2; mv1[vi][vj] = m2;
        float nvy = vyR[vi][vj] + DTC * buoL[vi][vj] * (d1 + m1 + d2 + m2);
        float d3 = (C1C * (sxyR[hy][hx] - sxyR[hy - 1][hx]) +
                    C2C * (sxyR[hy + 1][hx] - sxyR[hy - 2][hx])) * RDX;   // dmy(sxy)
        float m3 = by * mv2[vi][vj] + (by - 1.0f) * d3; mv2[vi][vj] = m3;
        float d4 = (C1C * (sxxR[hy][hx + 1] - sxxR[hy][hx]) +
                    C2C * (sxxR[hy][hx + 2] - sxxR[hy][hx - 1])) * RDX;   // dpx(sxx)
        float m4 = bx * mv3[vi][vj] + (bx - 1.0f) * d4; mv3[vi][vj] = m4;
        float nvx = vxR[vi][vj] + DTC * buoL[vi][vj] * (d3 + m3 + d4 + m4);
        if (y == sy && x == sx) nvy += amp;
        vyR[vi][vj] = nvy; vxR[vi][vj] = nvx;
    };

    auto doS = [&](int ly, int lx, ull* q, unsigned tag, bool pub) {
        int vi = ly + 2, vj = lx + 2;
        float by = byL[vi], bx = bxL[vj];
        float d, m;
        d = (C1C * (vyR[vi][vj] - vyR[vi - 1][vj]) +
             C2C * (vyR[vi + 1][vj] - vyR[vi - 2][vj])) * RDX;            // dmy(vy)
        m = by * ms0[ly][lx] + (by - 1.0f) * d; ms0[ly][lx] = m;
        float dvy_dy = d + m;
        d = (C1C * (vxR[vi][vj] - vxR[vi][vj - 1]) +
             C2C * (vxR[vi][vj + 1] - vxR[vi][vj - 2])) * RDX;            // dmx(vx)
        m = bx * ms1[ly][lx] + (bx - 1.0f) * d; ms1[ly][lx] = m;
        float dvx_dx = d + m;
        float nsyy = syyR[ly + 4][lx + 4] + DTC * (lp2mL[ly][lx] * dvy_dy + lamL[ly][lx] * dvx_dx);
        float nsxx = sxxR[ly + 4][lx + 4] + DTC * (lp2mL[ly][lx] * dvx_dx + lamL[ly][lx] * dvy_dy);
        d = (C1C * (vyR[vi][vj + 1] - vyR[vi][vj]) +
             C2C * (vyR[vi][vj + 2] - vyR[vi][vj - 1])) * RDX;            // dpx(vy)
        m = bx * ms2[ly][lx] + (bx - 1.0f) * d; ms2[ly][lx] = m;
        float dvy_dx = d + m;
        d = (C1C * (vxR[vi + 1][vj] - vxR[vi][vj]) +
             C2C * (vxR[vi + 2][vj] - vxR[vi - 1][vj])) * RDX;            // dpy(vx)
        m = by * ms3[ly][lx] + (by - 1.0f) * d; ms3[ly][lx] = m;
        float dvx_dy = d + m;
        float nsxy = sxyR[ly + 4][lx + 4] + DTC * muL[ly][lx] * (dvy_dx + dvx_dy);
        syyR[ly + 4][lx + 4] = nsyy;
        sxxR[ly + 4][lx + 4] = nsxx;
        sxyR[ly + 4][lx + 4] = nsxy;
        if (pub) {
            // packed 2-word record (each 8B half self-tagged), ONE 16B store
            // at 16B stride: adjacent cells -> adjacent lanes -> coalescing.
            int gi = (y0 + ly) * PITCH + (x0 + lx);
            ull* c = q + (size_t)gi * RECU;
            unsigned syyb = __float_as_uint(nsyy);
            unsigned sxxb = __float_as_uint(nsxx);
            unsigned sxyb = __float_as_uint(nsxy);
            ull t16 = (ull)(tag & 0xffffu) << 48;
            ull w0 = t16 | ((ull)(sxxb >> 16) << 32) | (ull)syyb;
            ull w1 = t16 | ((ull)(sxxb & 0xffffu) << 32) | (ull)sxyb;
            cstore16(c, w0, w1);
        }
    };

    for (int t = 0; t < NT; ++t) {
        const float amp_t = amps[s * NT + t];

        // ---- B-issue: one 16B pull load per cell, fired up front; the
        //      latency hides under the A-phase compute ----
        const ull* bb = strips + (size_t)(((t ^ 1) & 1) * NSHOT + s) * RECU * FSTRIDE;
        const unsigned want16 = (unsigned)t & 0xffffu;
        const ull* qp0 = bb + (size_t)qg0 * RECU;
        uint4v r0;
        if (hq0) r0 = cload16_issue(qp0);

        // ---- A: velocity core (block-local; overlaps in-flight pull) ----
        for (int i = tid; i < nCore; i += NTHR) {
            int r = i / cw, c = i - r * cw;
            doV(cy0 + r, cx0 + c, amp_t);
        }

        // ---- B-resolve: wait, tag-check both self-tagged halves, spin only
        //      if the neighbor is late; reconstruct sxx bit-exactly ----
        if (hq0) {
            cload16_wait(r0);
            while (((r0.y >> 16) != want16) || ((r0.w >> 16) != want16)) {
                __builtin_amdgcn_s_sleep(1);
                r0 = cload16_sync(qp0);
            }
            syyF[qo0] = __uint_as_float(r0.x);
            sxyF[qo0] = __uint_as_float(r0.z);
            sxxF[qo0] = __uint_as_float(((r0.y & 0xffffu) << 16) | (r0.w & 0xffffu));
        }
        __syncthreads();

        // ---- C: velocity ring (+2 redundant, needs the pulled halo) ----
        for (int i = tid; i < nRing; i += NTHR) {
            int y, x, j = i;
            if (j < nTop)           { y = vy0 + j / W2;     x = vx0 + j % W2; }
            else { j -= nTop;
            if (j < nBot)           { y = cy1 + j / W2;     x = vx0 + j % W2; }
            else { j -= nBot;
            if (j < nLeft)          { y = cy0 + j / leftW;  x = vx0 + j % leftW; }
            else { j -= nLeft;        y = cy0 + j / rightW; x = cx1 + j % rightW; } } }
            doV(y, x, amp_t);
        }
        __syncthreads();

        if (hasRec) out[recOff + t] = vyR[rvi][rvj];

        // ---- D1: boundary stress (depth<4), publish immediately (tag t+1) ----
        {
            ull* pb = strips + (size_t)((t & 1) * NSHOT + s) * RECU * FSTRIDE;
            const unsigned tag = (unsigned)(t + 1);
            const int midH = h - 8;
            const int nT4 = 4 * w, nB4 = 4 * w, nL4 = midH * 4;
            const int nD1 = nT4 + nB4 + 2 * nL4;
            for (int i = tid; i < nD1; i += NTHR) {
                int ly, lx, j = i;
                if (j < nT4)      { ly = j / w;           lx = j - (j / w) * w; }
                else { j -= nT4;
                if (j < nB4)      { ly = h - 4 + j / w;   lx = j - (j / w) * w; }
                else { j -= nB4;
                if (j < nL4)      { ly = 4 + (j >> 2);    lx = j & 3; }
                else { j -= nL4;    ly = 4 + (j >> 2);    lx = w - 4 + (j & 3); } } }
                doS(ly, lx, pb, tag, true);
            }
            // ---- D2: interior stress (off the inter-block critical path) ----
            const int w8 = w - 8, nD2 = midH * w8;
            for (int i = tid; i < nD2; i += NTHR) {
                int r = i / w8, c = i - r * w8;
                doS(4 + r, 4 + c, pb, 0u, false);
            }
        }
        __syncthreads();
    }
}

// ------------------------------ fallback path (R1, proven) ------------------

__global__ __launch_bounds__(256)
void vel_kernel(float* __restrict__ ws, const float* __restrict__ params,
                const float* __restrict__ bdec, const float* __restrict__ amps,
                const int* __restrict__ sloc, int t) {
    int x = blockIdx.x * 64 + threadIdx.x;
    int y = blockIdx.y * 4 + threadIdx.y;
    int s = blockIdx.z;
    if (x >= NXP) return;
    float* F = ws + (size_t)s * 13 * FSTRIDE;
    float* vy = F; float* vx = F + FSTRIDE;
    const float* syy = F + 2 * FSTRIDE;
    const float* sxx = F + 3 * FSTRIDE;
    const float* sxy = F + 4 * FSTRIDE;
    float* msyy_y = F + 9 * FSTRIDE;  float* msxy_x = F + 10 * FSTRIDE;
    float* msxy_y = F + 11 * FSTRIDE; float* msxx_x = F + 12 * FSTRIDE;
    float by = bdec[y], bx = bdec[NYP + x];
    int idx = y * PITCH + x;
    auto ldf2 = [&](const float* f, int yy, int xx) {
        return (yy >= 0 && yy < NYP && xx >= 0 && xx < NXP) ? f[yy * PITCH + xx] : 0.0f;
    };
    float buoy = params[3 * FSTRIDE + idx];
    float d, m;
    d = (C1C * (ldf2(syy,y+1,x) - ldf2(syy,y,x)) + C2C * (ldf2(syy,y+2,x) - ldf2(syy,y-1,x))) * RDX;
    m = by * msyy_y[idx] + (by - 1.0f) * d; msyy_y[idx] = m;
    float a1 = d + m;
    d = (C1C * (ldf2(sxy,y,x) - ldf2(sxy,y,x-1)) + C2C * (ldf2(sxy,y,x+1) - ldf2(sxy,y,x-2))) * RDX;
    m = bx * msxy_x[idx] + (bx - 1.0f) * d; msxy_x[idx] = m;
    float nvy = vy[idx] + DTC * buoy * (a1 + d + m);
    d = (C1C * (ldf2(sxy,y,x) - ldf2(sxy,y-1,x)) + C2C * (ldf2(sxy,y+1,x) - ldf2(sxy,y-2,x))) * RDX;
    m = by * msxy_y[idx] + (by - 1.0f) * d; msxy_y[idx] = m;
    float a2 = d + m;
    d = (C1C * (ldf2(sxx,y,x+1) - ldf2(sxx,y,x)) + C2C * (ldf2(sxx,y,x+2) - ldf2(sxx,y,x-1))) * RDX;
    m = bx * msxx_x[idx] + (bx - 1.0f) * d; msxx_x[idx] = m;
    float nvx = vx[idx] + DTC * buoy * (a2 + d + m);
    int sy = sloc[s * 2 + 0] + PML, sx = sloc[s * 2 + 1] + PML;
    if (y == sy && x == sx) nvy += amps[s * NT + t];
    vy[idx] = nvy; vx[idx] = nvx;
}

__global__ __launch_bounds__(256)
void str_kernel(float* __restrict__ ws, const float* __restrict__ params,
                const float* __restrict__ bdec, const int* __restrict__ rloc,
                float* __restrict__ out, int t) {
    int x = blockIdx.x * 64 + threadIdx.x;
    int y = blockIdx.y * 4 + threadIdx.y;
    int s = blockIdx.z;
    float* F = ws + (size_t)s * 13 * FSTRIDE;
    const float* vy = F; const float* vx = F + FSTRIDE;
    float* syy = F + 2 * FSTRIDE; float* sxx = F + 3 * FSTRIDE; float* sxy = F + 4 * FSTRIDE;
    float* mvyy = F + 5 * FSTRIDE; float* mvyx = F + 6 * FSTRIDE;
    float* mvxy = F + 7 * FSTRIDE; float* mvxx = F + 8 * FSTRIDE;
    if (blockIdx.x == 0 && blockIdx.y == 0) {
        int tid = threadIdx.y * 64 + threadIdx.x;
        if (tid < NREC) {
            int ry = rloc[(s * NREC + tid) * 2 + 0] + PML;
            int rx = rloc[(s * NREC + tid) * 2 + 1] + PML;
            out[(s * NREC + tid) * NT + t] = vy[ry * PITCH + rx];
        }
    }
    if (x >= NXP) return;
    auto ldf2 = [&](const float* f, int yy, int xx) {
        return (yy >= 0 && yy < NYP && xx >= 0 && xx < NXP) ? f[yy * PITCH + xx] : 0.0f;
    };
    float by = bdec[y], bx = bdec[NYP + x];
    int idx = y * PITCH + x;
    float lam = params[idx], lp2m = params[FSTRIDE + idx], muv = params[2 * FSTRIDE + idx];
    float d, m;
    d = (C1C * (ldf2(vy,y,x) - ldf2(vy,y-1,x)) + C2C * (ldf2(vy,y+1,x) - ldf2(vy,y-2,x))) * RDX;
    m = by * mvyy[idx] + (by - 1.0f) * d; mvyy[idx] = m;
    float dvy_dy = d + m;
    d = (C1C * (ldf2(vx,y,x) - ldf2(vx,y,x-1)) + C2C * (ldf2(vx,y,x+1) - ldf2(vx,y,x-2))) * RDX;
    m = bx * mvxx[idx] + (bx - 1.0f) * d; mvxx[idx] = m;
    float dvx_dx = d + m;
    syy[idx] += DTC * (lp2m * dvy_dy + lam * dvx_dx);
    sxx[idx] += DTC * (lp2m * dvx_dx + lam * dvy_dy);
    d = (C1C * (ldf2(vy,y,x+1) - ldf2(vy,y,x)) + C2C * (ldf2(vy,y,x+2) - ldf2(vy,y,x-1))) * RDX;
    m = bx * mvyx[idx] + (bx - 1.0f) * d; mvyx[idx] = m;
    float dvy_dx = d + m;
    d = (C1C * (ldf2(vx,y+1,x) - ldf2(vx,y,x)) + C2C * (ldf2(vx,y+2,x) - ldf2(vx,y-1,x))) * RDX;
    m = by * mvxy[idx] + (by - 1.0f) * d; mvxy[idx] = m;
    float dvx_dy = d + m;
    sxy[idx] += DTC * muv * (dvy_dx + dvx_dy);
}

// ----------------------------------------------------------------------------

extern "C" void kernel_launch(void* const* d_in, const int* in_sizes, int n_in,
                              void* d_out, int out_size, void* d_ws, size_t ws_size,
                              hipStream_t stream) {
    const float* lamb = (const float*)d_in[0];
    const float* mu   = (const float*)d_in[1];
    const float* buo  = (const float*)d_in[2];
    const float* amps = (const float*)d_in[3];
    const int*   sloc = (const int*)d_in[4];
    const int*   rloc = (const int*)d_in[5];
    float* out = (float*)d_out;

    float* wsf = (float*)d_ws;
    // layout: [strips: 8*FSTRIDE ull (2 parities x 2 shots x 2-ull packed
    //          16B cell records)]  (persist path computes params/decay
    //          inline; region after strips unused there but kept in the
    //          `needed` check for layout parity)
    ull*   strips = (ull*)wsf;
    size_t needed = ((size_t)36 * FSTRIDE + NYP + NXP) * sizeof(float);

    if (ws_size >= needed) {
        (void)hipMemsetAsync(strips, 0, (size_t)8 * FSTRIDE * sizeof(ull), stream);
        void* args[] = {&strips, &lamb, &mu, &buo, &amps, &sloc, &rloc, &out};
        (void)hipLaunchCooperativeKernel((void*)persist6_kernel, dim3(NSHOT * TX * TY),
                                         dim3(NTHR), args, 0, stream);
    } else {
        dim3 pib(256, 1, 1), pig((NXP + 255) / 256, NYP, 1);
        float* statef = wsf + 64;
        float* paramf = wsf + 64 + (size_t)26 * FSTRIDE;
        float* bdecf  = wsf + 64 + (size_t)30 * FSTRIDE;
        (void)hipMemsetAsync(statef, 0, (size_t)26 * FSTRIDE * sizeof(float), stream);
        init_params_kernel<<<pig, pib, 0, stream>>>(lamb, mu, buo, paramf);
        init_decay_kernel<<<(NYP + NXP + 255) / 256, 256, 0, stream>>>(bdecf);
        dim3 blk(64, 4, 1), grd((NXP + 63) / 64, NYP / 4, NSHOT);
        for (int t = 0; t < NT; ++t) {
            vel_kernel<<<grd, blk, 0, stream>>>(statef, paramf, bdecf, amps, sloc, t);
            str_kernel<<<grd, blk, 0, stream>>>(statef, paramf, bdecf, rloc, out, t);
        }
    }
}

// Round 12
// 438.167 us; speedup vs baseline: 1.9376x; 1.0003x over previous
//
#include <hip/hip_runtime.h>

// ---------------------------------------------------------------------------
// Elastic 2D velocity-stress staggered FD + C-PML, 2 shots, 128 steps.
// Round 21: R20 base (371us dispatch, passed) + END-OF-STEP BARRIER WITHOUT
// VMCNT DRAIN. Model state: traffic at structural floor (WRITE 248.6e3 KB ==
// ideal 16B/cell coalesced; 5th exact prediction); dur/step 2.90us = compute
// 1.3 + traffic 0.9 + sync 0.7. The end-of-step __syncthreads drains every
// publish store (~0.5-0.9us coherence round trip) with ALL waves blocked --
// semantically unneeded: protocol ordering is value-based (tag-in-data+spin),
// and same-thread store ordering is in-order vmcnt. Replacing ONLY that
// barrier with `s_waitcnt lgkmcnt(0); s_barrier` lets publish stores ride
// into step t+1 where cload16_wait's vmcnt(0) (AFTER the A-phase) drains
// them -- store latency hides under compute. (R12's similar attempt was
// confounded with LDS-stride changes + 3-load spin; R20's single-store/
// single-load structure is the clean case.)
//  - R20: 16B-stride records; WRITE -45% as modeled, coalescing confirmed.
//  - R19/R18: transaction cuts; each landed exactly as modeled.
// ---------------------------------------------------------------------------

typedef unsigned long long ull;
typedef __attribute__((ext_vector_type(4))) unsigned int uint4v;

#define NYI   300
#define NXI   300
#define PML   20
#define NYP   340
#define NXP   340
#define NT    128
#define DXC   5.0f
#define DTC   0.001f
#define NSHOT 2
#define NREC  32
#define C1C   (9.0f / 8.0f)
#define C2C   (-1.0f / 24.0f)
#define RDX   (1.0f / 5.0f)

#define PITCH   344
#define FSTRIDE (NYP * PITCH)
#define RECU    2            /* ulls per cell record (16B, packed) */

// tile grid per shot: 8 x 16 tiles
#define TX 8
#define TY 16
#define TW 43
#define TH 22
#define MH 30
#define MW 52
#define VH 26
#define VW 48
#define IH 22
#define IW 44

#define NTHR 1024

// 16B system-coherent store: one fabric transaction per cell record; with
// 16B-stride records adjacent lanes are contiguous -> intra-wave coalescing.
__device__ __forceinline__ void cstore16(ull* p, ull w0, ull w1) {
    uint4v v;
    v.x = (unsigned)w0; v.y = (unsigned)(w0 >> 32);
    v.z = (unsigned)w1; v.w = (unsigned)(w1 >> 32);
    asm volatile("global_store_dwordx4 %0, %1, off sc0 sc1"
                 :: "v"(p), "v"(v) : "memory");
}
// 16B system-coherent load, issue-only (no wait): latency hides under compute.
__device__ __forceinline__ uint4v cload16_issue(const ull* p) {
    uint4v r;
    asm volatile("global_load_dwordx4 %0, %1, off sc0 sc1"
                 : "=v"(r) : "v"(p) : "memory");
    return r;
}
// Wait for the issued load (drains in-flight publish stores too -- in-order
// vmcnt; they have had the whole A-phase to complete). "+v" makes every
// later use depend on this asm.
__device__ __forceinline__ void cload16_wait(uint4v& r) {
    asm volatile("s_waitcnt vmcnt(0)" : "+v"(r) :: "memory");
}
// Combined load+wait for the spin path.
__device__ __forceinline__ uint4v cload16_sync(const ull* p) {
    uint4v r;
    asm volatile("global_load_dwordx4 %0, %1, off sc0 sc1\n\ts_waitcnt vmcnt(0)"
                 : "=v"(r) : "v"(p) : "memory");
    return r;
}
// Barrier that drains only LDS: publish stores ride across into next step.
__device__ __forceinline__ void barrier_lds() {
    asm volatile("s_waitcnt lgkmcnt(0)\n\ts_barrier" ::: "memory");
}

__device__ __forceinline__ float decay_at(int idx) {
    float fx = (float)idx;
    float lo = fminf(fmaxf(((float)PML - fx) / (float)PML, 0.0f), 1.0f);
    float hi = fminf(fmaxf((fx - (float)(NYP - 1 - PML)) / (float)PML, 0.0f), 1.0f);
    float mx = fmaxf(lo, hi);
    float d0 = 3.0f * 2000.0f / (2.0f * (float)PML * DXC) * logf(1.0f / 1e-6f);
    return expf(-d0 * mx * mx * DTC);
}
__device__ __forceinline__ int clampi(int v, int hi) {
    return v < 0 ? 0 : (v > hi ? hi : v);
}

__global__ void init_params_kernel(const float* __restrict__ lamb,
                                   const float* __restrict__ mu,
                                   const float* __restrict__ buo,
                                   float* __restrict__ params) {
    int x = blockIdx.x * blockDim.x + threadIdx.x;
    int y = blockIdx.y;
    if (x >= NXP || y >= NYP) return;
    int cy = y - PML; cy = cy < 0 ? 0 : (cy > NYI - 1 ? NYI - 1 : cy);
    int cx = x - PML; cx = cx < 0 ? 0 : (cx > NXI - 1 ? NXI - 1 : cx);
    float l = lamb[cy * NXI + cx];
    float m = mu[cy * NXI + cx];
    float b = buo[cy * NXI + cx];
    int idx = y * PITCH + x;
    params[0 * FSTRIDE + idx] = l;
    params[1 * FSTRIDE + idx] = l + 2.0f * m;
    params[2 * FSTRIDE + idx] = m;
    params[3 * FSTRIDE + idx] = b;
}

__global__ void init_decay_kernel(float* __restrict__ bdec) {
    int i = blockIdx.x * blockDim.x + threadIdx.x;
    if (i >= NYP + NXP) return;
    int idx = (i < NYP) ? i : i - NYP;
    bdec[i] = decay_at(idx);
}

__global__ __launch_bounds__(NTHR)
void persist6_kernel(ull* __restrict__ strips, const float* __restrict__ lamb,
                     const float* __restrict__ mu, const float* __restrict__ buo,
                     const float* __restrict__ amps,
                     const int* __restrict__ sloc, const int* __restrict__ rloc,
                     float* __restrict__ out) {
    __shared__ float syyR[MH][MW], sxxR[MH][MW], sxyR[MH][MW];
    __shared__ float vyR[VH][VW], vxR[VH][VW];
    __shared__ float mv0[VH][VW], mv1[VH][VW], mv2[VH][VW], mv3[VH][VW];
    __shared__ float ms0[IH][IW], ms1[IH][IW], ms2[IH][IW], ms3[IH][IW];
    __shared__ float buoL[VH][VW];
    __shared__ float lamL[IH][IW], lp2mL[IH][IW], muL[IH][IW];
    __shared__ float byL[VH], bxL[VW];

    const int tid = threadIdx.x;
    const int s = blockIdx.x >> 7, tile = blockIdx.x & 127;
    const int txi = tile & 7, tyi = tile >> 3;
    const int x0 = txi * TW, x1 = min(x0 + TW, NXP);
    const int y0 = tyi * TH, y1 = min(y0 + TH, NYP);
    const int w = x1 - x0, h = y1 - y0;

    // ---- zero LDS state; compute params/decay directly into LDS ----
    for (int i = tid; i < MH * MW; i += NTHR) {
        int r = i / MW, c = i - r * MW;
        syyR[r][c] = 0.0f; sxxR[r][c] = 0.0f; sxyR[r][c] = 0.0f;
    }
    for (int i = tid; i < VH * VW; i += NTHR) {
        int r = i / VW, c = i - r * VW;
        vyR[r][c] = 0.0f; vxR[r][c] = 0.0f;
        mv0[r][c] = 0.0f; mv1[r][c] = 0.0f; mv2[r][c] = 0.0f; mv3[r][c] = 0.0f;
        buoL[r][c] = 0.0f;
    }
    for (int i = tid; i < IH * IW; i += NTHR) {
        int r = i / IW, c = i - r * IW;
        ms0[r][c] = 0.0f; ms1[r][c] = 0.0f; ms2[r][c] = 0.0f; ms3[r][c] = 0.0f;
    }
    if (tid < VH) {
        int y = y0 - 2 + tid; y = min(max(y, 0), NYP - 1);
        byL[tid] = decay_at(y);
    } else if (tid >= 64 && tid < 64 + VW) {
        int i = tid - 64, x = x0 - 2 + i; x = min(max(x, 0), NXP - 1);
        bxL[i] = decay_at(x);
    }
    __syncthreads();
    {
        int ry0v = max(y0 - 2, 0), ry1v = min(y1 + 2, NYP);
        int rx0v = max(x0 - 2, 0), rx1v = min(x1 + 2, NXP);
        int rh = ry1v - ry0v, rw = rx1v - rx0v;
        for (int i = tid; i < rh * rw; i += NTHR) {
            int r = i / rw, c = i - r * rw;
            int y = ry0v + r, x = rx0v + c;
            int cy = clampi(y - PML, NYI - 1), cx = clampi(x - PML, NXI - 1);
            buoL[y - y0 + 2][x - x0 + 2] = buo[cy * NXI + cx];
        }
        for (int i = tid; i < h * w; i += NTHR) {
            int r = i / w, c = i - r * w;
            int cy = clampi(y0 + r - PML, NYI - 1), cx = clampi(x0 + c - PML, NXI - 1);
            float l = lamb[cy * NXI + cx];
            float m = mu[cy * NXI + cx];
            lamL[r][c] = l;
            lp2mL[r][c] = l + 2.0f * m;
            muL[r][c] = m;
        }
    }

    const int sy = sloc[s * 2 + 0] + PML;
    const int sx = sloc[s * 2 + 1] + PML;

    bool hasRec = false; int recOff = 0, rvi = 0, rvj = 0;
    if (tid < NSHOT * NREC) {
        int rs = tid >> 5, rr = tid & 31;
        if (rs == s) {
            int ry = rloc[(rs * NREC + rr) * 2 + 0] + PML;
            int rx = rloc[(rs * NREC + rr) * 2 + 1] + PML;
            if (ry >= y0 && ry < y1 && rx >= x0 && rx < x1) {
                hasRec = true; recOff = (rs * NREC + rr) * NT;
                rvi = ry - y0 + 2; rvj = rx - x0 + 2;
            }
        }
    }
    __syncthreads();

    // region geometry (identical to R6/R7, validated)
    const int vy0 = max(y0 - 2, 0), vy1 = min(y1 + 2, NYP);
    const int vx0 = max(x0 - 2, 0), vx1 = min(x1 + 2, NXP);
    const int cy0 = y0 + 2, cy1 = y1 - 2, cx0 = x0 + 2, cx1 = x1 - 2;
    const int cw = cx1 - cx0, ch = cy1 - cy0, nCore = cw * ch;
    const int W2 = vx1 - vx0;
    const int topH = cy0 - vy0, botH = vy1 - cy1;
    const int leftW = cx0 - vx0, rightW = vx1 - cx1;
    const int nTop = topH * W2, nBot = botH * W2;
    const int nLeft = ch * leftW, nRight = ch * rightW;
    const int nRing = nTop + nBot + nLeft + nRight;
    const int py0 = max(y0 - 4, 0), py1 = min(y1 + 4, NYP);
    const int px0 = max(x0 - 4, 0), px1 = min(x1 + 4, NXP);
    const int W4 = px1 - px0;
    const int ptH = y0 - py0, pbH = py1 - y1;
    const int plW = x0 - px0, prW = px1 - x1;
    const int nPT = ptH * W4, nPB = pbH * W4, nPL = h * plW, nPR = h * prW;
    const int nPull = nPT + nPB + nPL + nPR;

    // ---- hoisted pull-cell decode (time-invariant; nPull <= 584 < 1024) ----
    const bool hq0 = tid < nPull;
    int qg0 = 0, qo0 = 0;
    if (hq0) {
        int j = tid, y, x;
        if (j < nPT)            { y = py0 + j / W4;  x = px0 + j % W4; }
        else { j -= nPT;
        if (j < nPB)            { y = y1 + j / W4;   x = px0 + j % W4; }
        else { j -= nPB;
        if (j < nPL)            { y = y0 + j / plW;  x = px0 + j % plW; }
        else { j -= nPL;          y = y0 + j / prW;  x = x1 + j % prW; } } }
        qg0 = y * PITCH + x;
        qo0 = (y - y0 + 4) * MW + (x - x0 + 4);
    }
    float* const syyF = &syyR[0][0];
    float* const sxxF = &sxxR[0][0];
    float* const sxyF = &sxyR[0][0];

    auto doV = [&](int y, int x, float amp) {
        int hy = y - y0 + 4, hx = x - x0 + 4;
        int vi = y - y0 + 2, vj = x - x0 + 2;
        float by = byL[vi], bx = bxL[vj];
        float d1 = (C1C * (syyR[hy + 1][hx] - syyR[hy][hx]) +
                    C2C * (syyR[hy + 2][hx] - syyR[hy - 1][hx])) * RDX;   // dpy(syy)
        float m1 = by * mv0[vi][vj] + (by - 1.0f) * d1; mv0[vi][vj] = m1;
        float d2 = (C1C * (sxyR[hy][hx] - sxyR[hy][hx - 1]) +
                    C2C * (sxyR[hy][hx + 1] - sxyR[hy][hx - 2])) * RDX;   // dmx(sxy)
        float m2 = bx * mv1[vi][vj] + (bx - 1.0f) * d2; mv1[vi][vj] = m2;
        float nvy = vyR[vi][vj] + DTC * buoL[vi][vj] * (d1 + m1 + d2 + m2);
        float d3 = (C1C * (sxyR[hy][hx] - sxyR[hy - 1][hx]) +
                    C2C * (sxyR[hy + 1][hx] - sxyR[hy - 2][hx])) * RDX;   // dmy(sxy)
        float m3 = by * mv2[vi][vj] + (by - 1.0f) * d3; mv2[vi][vj] = m3;
        float d4 = (C1C * (sxxR[hy][hx + 1] - sxxR[hy][hx]) +
                    C2C * (sxxR[hy][hx + 2] - sxxR[hy][hx - 1])) * RDX;   // dpx(sxx)
        float m4 = bx * mv3[vi][vj] + (bx - 1.0f) * d4; mv3[vi][vj] = m4;
        float nvx = vxR[vi][vj] + DTC * buoL[vi][vj] * (d3 + m3 + d4 + m4);
        if (y == sy && x == sx) nvy += amp;
        vyR[vi][vj] = nvy; vxR[vi][vj] = nvx;
    };

    auto doS = [&](int ly, int lx, ull* q, unsigned tag, bool pub) {
        int vi = ly + 2, vj = lx + 2;
        float by = byL[vi], bx = bxL[vj];
        float d, m;
        d = (C1C * (vyR[vi][vj] - vyR[vi - 1][vj]) +
             C2C * (vyR[vi + 1][vj] - vyR[vi - 2][vj])) * RDX;            // dmy(vy)
        m = by * ms0[ly][lx] + (by - 1.0f) * d; ms0[ly][lx] = m;
        float dvy_dy = d + m;
        d = (C1C * (vxR[vi][vj] - vxR[vi][vj - 1]) +
             C2C * (vxR[vi][vj + 1] - vxR[vi][vj - 2])) * RDX;            // dmx(vx)
        m = bx * ms1[ly][lx] + (bx - 1.0f) * d; ms1[ly][lx] = m;
        float dvx_dx = d + m;
        float nsyy = syyR[ly + 4][lx + 4] + DTC * (lp2mL[ly][lx] * dvy_dy + lamL[ly][lx] * dvx_dx);
        float nsxx = sxxR[ly + 4][lx + 4] + DTC * (lp2mL[ly][lx] * dvx_dx + lamL[ly][lx] * dvy_dy);
        d = (C1C * (vyR[vi][vj + 1] - vyR[vi][vj]) +
             C2C * (vyR[vi][vj + 2] - vyR[vi][vj - 1])) * RDX;            // dpx(vy)
        m = bx * ms2[ly][lx] + (bx - 1.0f) * d; ms2[ly][lx] = m;
        float dvy_dx = d + m;
        d = (C1C * (vxR[vi + 1][vj] - vxR[vi][vj]) +
             C2C * (vxR[vi + 2][vj] - vxR[vi - 1][vj])) * RDX;            // dpy(vx)
        m = by * ms3[ly][lx] + (by - 1.0f) * d; ms3[ly][lx] = m;
        float dvx_dy = d + m;
        float nsxy = sxyR[ly + 4][lx + 4] + DTC * muL[ly][lx] * (dvy_dx + dvx_dy);
        syyR[ly + 4][lx + 4] = nsyy;
        sxxR[ly + 4][lx + 4] = nsxx;
        sxyR[ly + 4][lx + 4] = nsxy;
        if (pub) {
            // packed 2-word record (each 8B half self-tagged), ONE 16B store
            // at 16B stride: adjacent cells -> adjacent lanes -> coalescing.
            int gi = (y0 + ly) * PITCH + (x0 + lx);
            ull* c = q + (size_t)gi * RECU;
            unsigned syyb = __float_as_uint(nsyy);
            unsigned sxxb = __float_as_uint(nsxx);
            unsigned sxyb = __float_as_uint(nsxy);
            ull t16 = (ull)(tag & 0xffffu) << 48;
            ull w0 = t16 | ((ull)(sxxb >> 16) << 32) | (ull)syyb;
            ull w1 = t16 | ((ull)(sxxb & 0xffffu) << 32) | (ull)sxyb;
            cstore16(c, w0, w1);
        }
    };

    for (int t = 0; t < NT; ++t) {
        const float amp_t = amps[s * NT + t];

        // ---- B-issue: one 16B pull load per cell, fired up front; the
        //      latency hides under the A-phase compute ----
        const ull* bb = strips + (size_t)(((t ^ 1) & 1) * NSHOT + s) * RECU * FSTRIDE;
        const unsigned want16 = (unsigned)t & 0xffffu;
        const ull* qp0 = bb + (size_t)qg0 * RECU;
        uint4v r0;
        if (hq0) r0 = cload16_issue(qp0);

        // ---- A: velocity core (block-local; overlaps in-flight pull AND
        //      the previous step's publish stores riding across the
        //      lgkm-only barrier) ----
        for (int i = tid; i < nCore; i += NTHR) {
            int r = i / cw, c = i - r * cw;
            doV(cy0 + r, cx0 + c, amp_t);
        }

        // ---- B-resolve: wait, tag-check both self-tagged halves, spin only
        //      if the neighbor is late; reconstruct sxx bit-exactly ----
        if (hq0) {
            cload16_wait(r0);
            while (((r0.y >> 16) != want16) || ((r0.w >> 16) != want16)) {
                __builtin_amdgcn_s_sleep(1);
                r0 = cload16_sync(qp0);
            }
            syyF[qo0] = __uint_as_float(r0.x);
            sxyF[qo0] = __uint_as_float(r0.z);
            sxxF[qo0] = __uint_as_float(((r0.y & 0xffffu) << 16) | (r0.w & 0xffffu));
        }
        __syncthreads();

        // ---- C: velocity ring (+2 redundant, needs the pulled halo) ----
        for (int i = tid; i < nRing; i += NTHR) {
            int y, x, j = i;
            if (j < nTop)           { y = vy0 + j / W2;     x = vx0 + j % W2; }
            else { j -= nTop;
            if (j < nBot)           { y = cy1 + j / W2;     x = vx0 + j % W2; }
            else { j -= nBot;
            if (j < nLeft)          { y = cy0 + j / leftW;  x = vx0 + j % leftW; }
            else { j -= nLeft;        y = cy0 + j / rightW; x = cx1 + j % rightW; } } }
            doV(y, x, amp_t);
        }
        __syncthreads();

        if (hasRec) out[recOff + t] = vyR[rvi][rvj];

        // ---- D1: boundary stress (depth<4), publish immediately (tag t+1) ----
        {
            ull* pb = strips + (size_t)((t & 1) * NSHOT + s) * RECU * FSTRIDE;
            const unsigned tag = (unsigned)(t + 1);
            const int midH = h - 8;
            const int nT4 = 4 * w, nB4 = 4 * w, nL4 = midH * 4;
            const int nD1 = nT4 + nB4 + 2 * nL4;
            for (int i = tid; i < nD1; i += NTHR) {
                int ly, lx, j = i;
                if (j < nT4)      { ly = j / w;           lx = j - (j / w) * w; }
                else { j -= nT4;
                if (j < nB4)      { ly = h - 4 + j / w;   lx = j - (j / w) * w; }
                else { j -= nB4;
                if (j < nL4)      { ly = 4 + (j >> 2);    lx = j & 3; }
                else { j -= nL4;    ly = 4 + (j >> 2);    lx = w - 4 + (j & 3); } } }
                doS(ly, lx, pb, tag, true);
            }
            // ---- D2: interior stress (off the inter-block critical path) ----
            const int w8 = w - 8, nD2 = midH * w8;
            for (int i = tid; i < nD2; i += NTHR) {
                int r = i / w8, c = i - r * w8;
                doS(4 + r, 4 + c, pb, 0u, false);
            }
        }
        // end-of-step barrier: LDS-only drain; publish stores ride across
        // and are drained by next step's cload16_wait (hidden under A).
        barrier_lds();
    }
}

// ------------------------------ fallback path (R1, proven) ------------------

__global__ __launch_bounds__(256)
void vel_kernel(float* __restrict__ ws, const float* __restrict__ params,
                const float* __restrict__ bdec, const float* __restrict__ amps,
                const int* __restrict__ sloc, int t) {
    int x = blockIdx.x * 64 + threadIdx.x;
    int y = blockIdx.y * 4 + threadIdx.y;
    int s = blockIdx.z;
    if (x >= NXP) return;
    float* F = ws + (size_t)s * 13 * FSTRIDE;
    float* vy = F; float* vx = F + FSTRIDE;
    const float* syy = F + 2 * FSTRIDE;
    const float* sxx = F + 3 * FSTRIDE;
    const float* sxy = F + 4 * FSTRIDE;
    float* msyy_y = F + 9 * FSTRIDE;  float* msxy_x = F + 10 * FSTRIDE;
    float* msxy_y = F + 11 * FSTRIDE; float* msxx_x = F + 12 * FSTRIDE;
    float by = bdec[y], bx = bdec[NYP + x];
    int idx = y * PITCH + x;
    auto ldf2 = [&](const float* f, int yy, int xx) {
        return (yy >= 0 && yy < NYP && xx >= 0 && xx < NXP) ? f[yy * PITCH + xx] : 0.0f;
    };
    float buoy = params[3 * FSTRIDE + idx];
    float d, m;
    d = (C1C * (ldf2(syy,y+1,x) - ldf2(syy,y,x)) + C2C * (ldf2(syy,y+2,x) - ldf2(syy,y-1,x))) * RDX;
    m = by * msyy_y[idx] + (by - 1.0f) * d; msyy_y[idx] = m;
    float a1 = d + m;
    d = (C1C * (ldf2(sxy,y,x) - ldf2(sxy,y,x-1)) + C2C * (ldf2(sxy,y,x+1) - ldf2(sxy,y,x-2))) * RDX;
    m = bx * msxy_x[idx] + (bx - 1.0f) * d; msxy_x[idx] = m;
    float nvy = vy[idx] + DTC * buoy * (a1 + d + m);
    d = (C1C * (ldf2(sxy,y,x) - ldf2(sxy,y-1,x)) + C2C * (ldf2(sxy,y+1,x) - ldf2(sxy,y-2,x))) * RDX;
    m = by * msxy_y[idx] + (by - 1.0f) * d; msxy_y[idx] = m;
    float a2 = d + m;
    d = (C1C * (ldf2(sxx,y,x+1) - ldf2(sxx,y,x)) + C2C * (ldf2(sxx,y,x+2) - ldf2(sxx,y,x-1))) * RDX;
    m = bx * msxx_x[idx] + (bx - 1.0f) * d; msxx_x[idx] = m;
    float nvx = vx[idx] + DTC * buoy * (a2 + d + m);
    int sy = sloc[s * 2 + 0] + PML, sx = sloc[s * 2 + 1] + PML;
    if (y == sy && x == sx) nvy += amps[s * NT + t];
    vy[idx] = nvy; vx[idx] = nvx;
}

__global__ __launch_bounds__(256)
void str_kernel(float* __restrict__ ws, const float* __restrict__ params,
                const float* __restrict__ bdec, const int* __restrict__ rloc,
                float* __restrict__ out, int t) {
    int x = blockIdx.x * 64 + threadIdx.x;
    int y = blockIdx.y * 4 + threadIdx.y;
    int s = blockIdx.z;
    float* F = ws + (size_t)s * 13 * FSTRIDE;
    const float* vy = F; const float* vx = F + FSTRIDE;
    float* syy = F + 2 * FSTRIDE; float* sxx = F + 3 * FSTRIDE; float* sxy = F + 4 * FSTRIDE;
    float* mvyy = F + 5 * FSTRIDE; float* mvyx = F + 6 * FSTRIDE;
    float* mvxy = F + 7 * FSTRIDE; float* mvxx = F + 8 * FSTRIDE;
    if (blockIdx.x == 0 && blockIdx.y == 0) {
        int tid = threadIdx.y * 64 + threadIdx.x;
        if (tid < NREC) {
            int ry = rloc[(s * NREC + tid) * 2 + 0] + PML;
            int rx = rloc[(s * NREC + tid) * 2 + 1] + PML;
            out[(s * NREC + tid) * NT + t] = vy[ry * PITCH + rx];
        }
    }
    if (x >= NXP) return;
    auto ldf2 = [&](const float* f, int yy, int xx) {
        return (yy >= 0 && yy < NYP && xx >= 0 && xx < NXP) ? f[yy * PITCH + xx] : 0.0f;
    };
    float by = bdec[y], bx = bdec[NYP + x];
    int idx = y * PITCH + x;
    float lam = params[idx], lp2m = params[FSTRIDE + idx], muv = params[2 * FSTRIDE + idx];
    float d, m;
    d = (C1C * (ldf2(vy,y,x) - ldf2(vy,y-1,x)) + C2C * (ldf2(vy,y+1,x) - ldf2(vy,y-2,x))) * RDX;
    m = by * mvyy[idx] + (by - 1.0f) * d; mvyy[idx] = m;
    float dvy_dy = d + m;
    d = (C1C * (ldf2(vx,y,x) - ldf2(vx,y,x-1)) + C2C * (ldf2(vx,y,x+1) - ldf2(vx,y,x-2))) * RDX;
    m = bx * mvxx[idx] + (bx - 1.0f) * d; mvxx[idx] = m;
    float dvx_dx = d + m;
    syy[idx] += DTC * (lp2m * dvy_dy + lam * dvx_dx);
    sxx[idx] += DTC * (lp2m * dvx_dx + lam * dvy_dy);
    d = (C1C * (ldf2(vy,y,x+1) - ldf2(vy,y,x)) + C2C * (ldf2(vy,y,x+2) - ldf2(vy,y,x-1))) * RDX;
    m = bx * mvyx[idx] + (bx - 1.0f) * d; mvyx[idx] = m;
    float dvy_dx = d + m;
    d = (C1C * (ldf2(vx,y+1,x) - ldf2(vx,y,x)) + C2C * (ldf2(vx,y+2,x) - ldf2(vx,y-1,x))) * RDX;
    m = by * mvxy[idx] + (by - 1.0f) * d; mvxy[idx] = m;
    float dvx_dy = d + m;
    sxy[idx] += DTC * muv * (dvy_dx + dvx_dy);
}

// ----------------------------------------------------------------------------

extern "C" void kernel_launch(void* const* d_in, const int* in_sizes, int n_in,
                              void* d_out, int out_size, void* d_ws, size_t ws_size,
                              hipStream_t stream) {
    const float* lamb = (const float*)d_in[0];
    const float* mu   = (const float*)d_in[1];
    const float* buo  = (const float*)d_in[2];
    const float* amps = (const float*)d_in[3];
    const int*   sloc = (const int*)d_in[4];
    const int*   rloc = (const int*)d_in[5];
    float* out = (float*)d_out;

    float* wsf = (float*)d_ws;
    // layout: [strips: 8*FSTRIDE ull (2 parities x 2 shots x 2-ull packed
    //          16B cell records)]  (persist path computes params/decay
    //          inline; region after strips unused there but kept in the
    //          `needed` check for layout parity)
    ull*   strips = (ull*)wsf;
    size_t needed = ((size_t)36 * FSTRIDE + NYP + NXP) * sizeof(float);

    if (ws_size >= needed) {
        (void)hipMemsetAsync(strips, 0, (size_t)8 * FSTRIDE * sizeof(ull), stream);
        void* args[] = {&strips, &lamb, &mu, &buo, &amps, &sloc, &rloc, &out};
        (void)hipLaunchCooperativeKernel((void*)persist6_kernel, dim3(NSHOT * TX * TY),
                                         dim3(NTHR), args, 0, stream);
    } else {
        dim3 pib(256, 1, 1), pig((NXP + 255) / 256, NYP, 1);
        float* statef = wsf + 64;
        float* paramf = wsf + 64 + (size_t)26 * FSTRIDE;
        float* bdecf  = wsf + 64 + (size_t)30 * FSTRIDE;
        (void)hipMemsetAsync(statef, 0, (size_t)26 * FSTRIDE * sizeof(float), stream);
        init_params_kernel<<<pig, pib, 0, stream>>>(lamb, mu, buo, paramf);
        init_decay_kernel<<<(NYP + NXP + 255) / 256, 256, 0, stream>>>(bdecf);
        dim3 blk(64, 4, 1), grd((NXP + 63) / 64, NYP / 4, NSHOT);
        for (int t = 0; t < NT; ++t) {
            vel_kernel<<<grd, blk, 0, stream>>>(statef, paramf, bdecf, amps, sloc, t);
            str_kernel<<<grd, blk, 0, stream>>>(statef, paramf, bdecf, rloc, out, t);
        }
    }
}